// Round 1
// baseline (1819.190 us; speedup 1.0000x reference)
//
#include <hip/hip_runtime.h>
#include <math.h>

#define B 128
#define N 512
#define H 512

__device__ __forceinline__ float sigmoidf_(float x){ return 1.0f/(1.0f+expf(-x)); }

// ---------------- Kernel 1: GRU step -> h_new (also written to out[1]) ----------------
__global__ __launch_bounds__(512) void k_gru(const float* __restrict__ dec,
    const float* __restrict__ lhh, const float* __restrict__ wih,
    const float* __restrict__ whh, const float* __restrict__ bih,
    const float* __restrict__ bhh, float* __restrict__ hnew,
    float* __restrict__ out_hh)
{
    __shared__ float xs[H], hs[H];
    int b = blockIdx.x, t = threadIdx.x;
    xs[t] = dec[b*H+t]; hs[t] = lhh[b*H+t];
    __syncthreads();
    float gx[3], gh[3];
    #pragma unroll
    for (int gi=0; gi<3; ++gi){
        int row = gi*H + t;
        const float4* wi = (const float4*)(wih + (size_t)row*H);
        const float4* wh = (const float4*)(whh + (size_t)row*H);
        float ax=0.f, ah=0.f;
        for (int k4=0;k4<H/4;++k4){
            float4 a = wi[k4], c = wh[k4];
            ax += a.x*xs[4*k4] + a.y*xs[4*k4+1] + a.z*xs[4*k4+2] + a.w*xs[4*k4+3];
            ah += c.x*hs[4*k4] + c.y*hs[4*k4+1] + c.z*hs[4*k4+2] + c.w*hs[4*k4+3];
        }
        gx[gi] = ax + bih[row];
        gh[gi] = ah + bhh[row];
    }
    float r = sigmoidf_(gx[0]+gh[0]);
    float z = sigmoidf_(gx[1]+gh[1]);
    float n = tanhf(gx[2] + r*gh[2]);
    float hv = (1.f-z)*n + z*hs[t];
    hnew[b*H+t] = hv;
    out_hh[b*H+t] = hv;
}

// ---- Kernel 2: broadcast-half biases: d_enc=h_new@Wenc_d^T, d_tgt=tgt@Wtgt_d^T, d_se=se@WptrSE^T ----
__global__ __launch_bounds__(512) void k_dbias(const float* __restrict__ hnew,
    const float* __restrict__ tgt, const float* __restrict__ sem,
    const float* __restrict__ encW, const float* __restrict__ tgtW,
    const float* __restrict__ ptrW,
    float* __restrict__ d_enc, float* __restrict__ d_tgt, float* __restrict__ d_se)
{
    __shared__ float a[H], c[H], s[H];
    int b = blockIdx.x, t = threadIdx.x;
    a[t] = hnew[b*H+t]; c[t] = tgt[b*H+t]; s[t] = sem[b*H+t];
    __syncthreads();
    const float4* we = (const float4*)(encW + (size_t)t*(2*H) + H);
    const float4* wt = (const float4*)(tgtW + (size_t)t*(2*H) + H);
    const float4* wp = (const float4*)(ptrW + (size_t)t*(3*H) + 2*H);
    float ae=0.f, at=0.f, as2=0.f;
    for (int k4=0;k4<H/4;++k4){
        float4 v;
        v = we[k4]; ae  += v.x*a[4*k4]+v.y*a[4*k4+1]+v.z*a[4*k4+2]+v.w*a[4*k4+3];
        v = wt[k4]; at  += v.x*c[4*k4]+v.y*c[4*k4+1]+v.z*c[4*k4+2]+v.w*c[4*k4+3];
        v = wp[k4]; as2 += v.x*s[4*k4]+v.y*s[4*k4+1]+v.z*s[4*k4+2]+v.w*s[4*k4+3];
    }
    d_enc[b*H+t]=ae; d_tgt[b*H+t]=at; d_se[b*H+t]=as2;
}

// ---- Kernel 3: fused enc+tgt attention scores (big GEMM + tanh·v epilogue, atomic h-split) ----
__global__ __launch_bounds__(256) void k_scores2(const float* __restrict__ A,
    const float* __restrict__ encW, const float* __restrict__ tgtW,
    const float* __restrict__ d_enc, const float* __restrict__ d_tgt,
    const float* __restrict__ enc_v, const float* __restrict__ tgt_v,
    float* __restrict__ sc_e, float* __restrict__ sc_t)
{
    __shared__ float As[64][36];   // [n][k], +4 pad
    __shared__ float We[32][68];   // [k][h], +4 pad (k-major: lane-consecutive h reads)
    __shared__ float Wt[32][68];
    int blk = blockIdx.x;
    int b = blk >> 6; int r = blk & 63; int nt = r >> 3; int ht = r & 7;
    int n0 = nt*64, h0 = ht*64;
    int t = threadIdx.x;
    int lane = t & 63, wave = t >> 6;
    int hq = lane & 15, ng = (wave<<2) | (lane>>4);
    int hl = hq*4, nl = ng*4;
    float acc_e[4][4] = {{0}}, acc_t[4][4] = {{0}};
    for (int kt = 0; kt < H/32; ++kt){
        int k0 = kt*32;
        for (int idx = t; idx < 512; idx += 256){
            int row = idx >> 3, c4 = idx & 7;
            float4 v = *(const float4*)&A[(size_t)(b*N + n0 + row)*H + k0 + c4*4];
            *(float4*)&As[row][c4*4] = v;
        }
        for (int idx = t; idx < 512; idx += 256){
            int hh = idx >> 3, c4 = idx & 7;
            float4 v = *(const float4*)&encW[(size_t)(h0+hh)*(2*H) + k0 + c4*4];
            We[c4*4+0][hh]=v.x; We[c4*4+1][hh]=v.y; We[c4*4+2][hh]=v.z; We[c4*4+3][hh]=v.w;
            float4 w = *(const float4*)&tgtW[(size_t)(h0+hh)*(2*H) + k0 + c4*4];
            Wt[c4*4+0][hh]=w.x; Wt[c4*4+1][hh]=w.y; Wt[c4*4+2][hh]=w.z; Wt[c4*4+3][hh]=w.w;
        }
        __syncthreads();
        for (int k4=0;k4<8;++k4){
            float av[4][4];
            #pragma unroll
            for (int i=0;i<4;++i)
                *(float4*)av[i] = *(const float4*)&As[nl+i][k4*4];
            #pragma unroll
            for (int j=0;j<4;++j){
                int kk = k4*4+j;
                float4 we = *(const float4*)&We[kk][hl];
                float4 wt = *(const float4*)&Wt[kk][hl];
                #pragma unroll
                for (int i=0;i<4;++i){
                    acc_e[i][0] += av[i][j]*we.x;
                    acc_e[i][1] += av[i][j]*we.y;
                    acc_e[i][2] += av[i][j]*we.z;
                    acc_e[i][3] += av[i][j]*we.w;
                    acc_t[i][0] += av[i][j]*wt.x;
                    acc_t[i][1] += av[i][j]*wt.y;
                    acc_t[i][2] += av[i][j]*wt.z;
                    acc_t[i][3] += av[i][j]*wt.w;
                }
            }
        }
        __syncthreads();
    }
    float de[4], ve[4], dt[4], vt[4];
    #pragma unroll
    for (int j=0;j<4;++j){
        int h = h0+hl+j;
        de[j]=d_enc[b*H+h]; ve[j]=enc_v[h];
        dt[j]=d_tgt[b*H+h]; vt[j]=tgt_v[h];
    }
    #pragma unroll
    for (int i=0;i<4;++i){
        float se=0.f, st=0.f;
        #pragma unroll
        for (int j=0;j<4;++j){
            se += ve[j]*tanhf(acc_e[i][j]+de[j]);
            st += vt[j]*tanhf(acc_t[i][j]+dt[j]);
        }
        #pragma unroll
        for (int off=1; off<16; off<<=1){
            se += __shfl_xor(se, off);
            st += __shfl_xor(st, off);
        }
        if (hq==0){
            atomicAdd(&sc_e[b*N + n0 + nl + i], se);
            atomicAdd(&sc_t[b*N + n0 + nl + i], st);
        }
    }
}

// ---------------- Kernel 4: softmax both score rows ----------------
__global__ __launch_bounds__(256) void k_softmax(const float* __restrict__ sc_e,
    const float* __restrict__ sc_t, float* __restrict__ w_e, float* __restrict__ w_t)
{
    __shared__ float buf[256];
    int b = blockIdx.x, t = threadIdx.x;
    // enc
    float x0 = sc_e[b*N+t], x1 = sc_e[b*N+t+256];
    float m = fmaxf(x0,x1);
    buf[t]=m; __syncthreads();
    for (int s2=128;s2>0;s2>>=1){ if(t<s2) buf[t]=fmaxf(buf[t],buf[t+s2]); __syncthreads(); }
    m = buf[0]; __syncthreads();
    float e0 = expf(x0-m), e1 = expf(x1-m);
    buf[t]=e0+e1; __syncthreads();
    for (int s2=128;s2>0;s2>>=1){ if(t<s2) buf[t]+=buf[t+s2]; __syncthreads(); }
    float inv = 1.0f/buf[0]; __syncthreads();
    w_e[b*N+t]=e0*inv; w_e[b*N+t+256]=e1*inv;
    // tgt
    x0 = sc_t[b*N+t]; x1 = sc_t[b*N+t+256];
    m = fmaxf(x0,x1);
    buf[t]=m; __syncthreads();
    for (int s2=128;s2>0;s2>>=1){ if(t<s2) buf[t]=fmaxf(buf[t],buf[t+s2]); __syncthreads(); }
    m = buf[0]; __syncthreads();
    e0 = expf(x0-m); e1 = expf(x1-m);
    buf[t]=e0+e1; __syncthreads();
    for (int s2=128;s2>0;s2>>=1){ if(t<s2) buf[t]+=buf[t+s2]; __syncthreads(); }
    inv = 1.0f/buf[0];
    w_t[b*N+t]=e0*inv; w_t[b*N+t+256]=e1*inv;
}

// ---------------- Kernel 5: context = attn @ static (both, n-split + atomic) ----------------
__global__ __launch_bounds__(256) void k_context(const float* __restrict__ A,
    const float* __restrict__ w_e, const float* __restrict__ w_t,
    float* __restrict__ ctx, float* __restrict__ ctxt)
{
    __shared__ float we[128], wt[128];
    int b = blockIdx.x >> 2, c = blockIdx.x & 3, t = threadIdx.x;
    int n0 = c*128;
    if (t < 128){ we[t]=w_e[b*N+n0+t]; wt[t]=w_t[b*N+n0+t]; }
    __syncthreads();
    float ae0=0.f, ae1=0.f, at0=0.f, at1=0.f;
    for (int n=0;n<128;++n){
        const float* ar = A + (size_t)(b*N + n0 + n)*H;
        float a0 = ar[t], a1 = ar[t+256];
        ae0 += we[n]*a0; ae1 += we[n]*a1;
        at0 += wt[n]*a0; at1 += wt[n]*a1;
    }
    atomicAdd(&ctx[b*H+t],      ae0); atomicAdd(&ctx[b*H+t+256],  ae1);
    atomicAdd(&ctxt[b*H+t],     at0); atomicAdd(&ctxt[b*H+t+256], at1);
}

// ------- Kernel 6: pointer biases d_pe = ctx@Wctx^T + d_se ; d_pt = ctxt@Wctx^T + d_se -------
__global__ __launch_bounds__(512) void k_dptr(const float* __restrict__ ctx,
    const float* __restrict__ ctxt, const float* __restrict__ d_se,
    const float* __restrict__ ptrW, float* __restrict__ d_pe, float* __restrict__ d_pt)
{
    __shared__ float cs[H], cts[H];
    int b = blockIdx.x, t = threadIdx.x;
    cs[t]=ctx[b*H+t]; cts[t]=ctxt[b*H+t];
    __syncthreads();
    const float4* wp = (const float4*)(ptrW + (size_t)t*(3*H) + H);
    float ae=0.f, at=0.f;
    for (int k4=0;k4<H/4;++k4){
        float4 v = wp[k4];
        ae += v.x*cs[4*k4]+v.y*cs[4*k4+1]+v.z*cs[4*k4+2]+v.w*cs[4*k4+3];
        at += v.x*cts[4*k4]+v.y*cts[4*k4+1]+v.z*cts[4*k4+2]+v.w*cts[4*k4+3];
    }
    float s0 = d_se[b*H+t];
    d_pe[b*H+t]=ae+s0; d_pt[b*H+t]=at+s0;
}

// ---- Kernel 7: pointer scores — ONE shared S GEMM, two tanh epilogues, out = 5*pe + pt ----
__global__ __launch_bounds__(256) void k_probs(const float* __restrict__ A,
    const float* __restrict__ ptrW, const float* __restrict__ d_pe,
    const float* __restrict__ d_pt, const float* __restrict__ ptr_v,
    float* __restrict__ probs)
{
    __shared__ float As[64][36];
    __shared__ float Wp[32][68];
    int blk = blockIdx.x;
    int b = blk >> 6; int r = blk & 63; int nt = r >> 3; int ht = r & 7;
    int n0 = nt*64, h0 = ht*64;
    int t = threadIdx.x;
    int lane = t & 63, wave = t >> 6;
    int hq = lane & 15, ng = (wave<<2) | (lane>>4);
    int hl = hq*4, nl = ng*4;
    float acc[4][4] = {{0}};
    for (int kt = 0; kt < H/32; ++kt){
        int k0 = kt*32;
        for (int idx = t; idx < 512; idx += 256){
            int row = idx >> 3, c4 = idx & 7;
            float4 v = *(const float4*)&A[(size_t)(b*N + n0 + row)*H + k0 + c4*4];
            *(float4*)&As[row][c4*4] = v;
        }
        for (int idx = t; idx < 512; idx += 256){
            int hh = idx >> 3, c4 = idx & 7;
            float4 v = *(const float4*)&ptrW[(size_t)(h0+hh)*(3*H) + k0 + c4*4];
            Wp[c4*4+0][hh]=v.x; Wp[c4*4+1][hh]=v.y; Wp[c4*4+2][hh]=v.z; Wp[c4*4+3][hh]=v.w;
        }
        __syncthreads();
        for (int k4=0;k4<8;++k4){
            float av[4][4];
            #pragma unroll
            for (int i=0;i<4;++i)
                *(float4*)av[i] = *(const float4*)&As[nl+i][k4*4];
            #pragma unroll
            for (int j=0;j<4;++j){
                int kk = k4*4+j;
                float4 wp = *(const float4*)&Wp[kk][hl];
                #pragma unroll
                for (int i=0;i<4;++i){
                    acc[i][0] += av[i][j]*wp.x;
                    acc[i][1] += av[i][j]*wp.y;
                    acc[i][2] += av[i][j]*wp.z;
                    acc[i][3] += av[i][j]*wp.w;
                }
            }
        }
        __syncthreads();
    }
    float de[4], dt[4], vv[4];
    #pragma unroll
    for (int j=0;j<4;++j){
        int h = h0+hl+j;
        de[j]=d_pe[b*H+h]; dt[j]=d_pt[b*H+h]; vv[j]=ptr_v[h];
    }
    #pragma unroll
    for (int i=0;i<4;++i){
        float pe=0.f, pt=0.f;
        #pragma unroll
        for (int j=0;j<4;++j){
            pe += vv[j]*tanhf(acc[i][j]+de[j]);
            pt += vv[j]*tanhf(acc[i][j]+dt[j]);
        }
        #pragma unroll
        for (int off=1; off<16; off<<=1){
            pe += __shfl_xor(pe, off);
            pt += __shfl_xor(pt, off);
        }
        if (hq==0){
            atomicAdd(&probs[b*N + n0 + nl + i], 5.0f*pe + pt);
        }
    }
}

extern "C" void kernel_launch(void* const* d_in, const int* in_sizes, int n_in,
                              void* d_out, int out_size, void* d_ws, size_t ws_size,
                              hipStream_t stream)
{
    (void)in_sizes; (void)n_in; (void)out_size; (void)ws_size;
    const float* A    = (const float*)d_in[0];   // static_hidden (B,N,H)
    const float* sem  = (const float*)d_in[1];   // state_embedding (B,1,H)
    const float* dec  = (const float*)d_in[2];   // decoder_hidden (B,1,H)
    const float* tgt  = (const float*)d_in[3];   // target_hidden (B,1,H)
    const float* lhh  = (const float*)d_in[4];   // last_hh (1,B,H)
    const float* ptrv = (const float*)d_in[5];   // (1,1,H)
    const float* ptrW = (const float*)d_in[6];   // (1,H,3H)
    const float* encv = (const float*)d_in[7];
    const float* encW = (const float*)d_in[8];   // (1,H,2H)
    const float* tgtv = (const float*)d_in[9];
    const float* tgtW = (const float*)d_in[10];  // (1,H,2H)
    const float* wih  = (const float*)d_in[11];  // (3H,H)
    const float* whh  = (const float*)d_in[12];
    const float* bih  = (const float*)d_in[13];
    const float* bhh  = (const float*)d_in[14];

    float* probs_out = (float*)d_out;            // (B,N)
    float* hh_out    = (float*)d_out + B*N;      // (1,B,H)

    float* ws = (float*)d_ws;
    const int S = B*H; // 65536
    float* hnew  = ws;
    float* d_enc = ws + (size_t)S;
    float* d_tgt = ws + (size_t)2*S;
    float* d_se  = ws + (size_t)3*S;
    float* sc_e  = ws + (size_t)4*S;
    float* sc_t  = ws + (size_t)5*S;
    float* ctx   = ws + (size_t)6*S;
    float* ctxt  = ws + (size_t)7*S;
    float* w_e   = ws + (size_t)8*S;
    float* w_t   = ws + (size_t)9*S;
    float* d_pe  = ws + (size_t)10*S;
    float* d_pt  = ws + (size_t)11*S;

    // zero atomic-accumulation targets (ws/d_out are poisoned 0xAA each call)
    hipMemsetAsync(sc_e, 0, (size_t)4*S*sizeof(float), stream);   // sc_e, sc_t, ctx, ctxt
    hipMemsetAsync(probs_out, 0, (size_t)B*N*sizeof(float), stream);

    k_gru<<<B, 512, 0, stream>>>(dec, lhh, wih, whh, bih, bhh, hnew, hh_out);
    k_dbias<<<B, 512, 0, stream>>>(hnew, tgt, sem, encW, tgtW, ptrW, d_enc, d_tgt, d_se);
    k_scores2<<<8192, 256, 0, stream>>>(A, encW, tgtW, d_enc, d_tgt, encv, tgtv, sc_e, sc_t);
    k_softmax<<<B, 256, 0, stream>>>(sc_e, sc_t, w_e, w_t);
    k_context<<<B*4, 256, 0, stream>>>(A, w_e, w_t, ctx, ctxt);
    k_dptr<<<B, 512, 0, stream>>>(ctx, ctxt, d_se, ptrW, d_pe, d_pt);
    k_probs<<<8192, 256, 0, stream>>>(A, ptrW, d_pe, d_pt, ptrv, probs_out);
}

// Round 2
// 825.043 us; speedup vs baseline: 2.2050x; 2.2050x over previous
//
#include <hip/hip_runtime.h>
#include <math.h>

#define B 128
#define N 512
#define H 512

typedef __attribute__((ext_vector_type(8))) short short8;
typedef __attribute__((ext_vector_type(4))) float floatx4;

__device__ __forceinline__ float sigmoidf_(float x){ return 1.0f/(1.0f+__expf(-x)); }

// tanh via exp, overflow-safe
__device__ __forceinline__ float fast_tanh(float x){
    float t = __expf(-2.0f*fabsf(x));
    float r = __fdividef(1.0f - t, 1.0f + t);
    return copysignf(r, x);
}

// fp32 -> bf16 RNE
__device__ __forceinline__ unsigned f2bf1(float f){
    unsigned u = __float_as_uint(f);
    u += 0x7FFFu + ((u>>16)&1u);
    return u>>16;
}
__device__ __forceinline__ unsigned pk2(float a, float b){
    return f2bf1(a) | (f2bf1(b)<<16);
}

// ---------------- Kernel 0: cast W static-halves to bf16 [h][k] k-contig ----------------
__global__ __launch_bounds__(256) void k_castw(const float* __restrict__ encW,
    const float* __restrict__ tgtW, const float* __restrict__ ptrW,
    unsigned short* __restrict__ We, unsigned short* __restrict__ Wt,
    unsigned short* __restrict__ Wp)
{
    int blk = blockIdx.x; int mat = blk >> 9; int row = blk & 511; int t = threadIdx.x;
    const float* src; unsigned short* dst; int pitch;
    if (mat==0){ src=encW; dst=We; pitch=2*H; }
    else if (mat==1){ src=tgtW; dst=Wt; pitch=2*H; }
    else { src=ptrW; dst=Wp; pitch=3*H; }
    float2 v = *(const float2*)&src[(size_t)row*pitch + 2*t];
    *(unsigned*)&dst[(size_t)row*H + 2*t] = pk2(v.x, v.y);
}

// ---------------- Kernel 1: GRU step -> h_new (also written to out[1]) ----------------
__global__ __launch_bounds__(512) void k_gru(const float* __restrict__ dec,
    const float* __restrict__ lhh, const float* __restrict__ wih,
    const float* __restrict__ whh, const float* __restrict__ bih,
    const float* __restrict__ bhh, float* __restrict__ hnew,
    float* __restrict__ out_hh)
{
    __shared__ float xs[H], hs[H];
    int b = blockIdx.x, t = threadIdx.x;
    xs[t] = dec[b*H+t]; hs[t] = lhh[b*H+t];
    __syncthreads();
    float gx[3], gh[3];
    #pragma unroll
    for (int gi=0; gi<3; ++gi){
        int row = gi*H + t;
        const float4* wi = (const float4*)(wih + (size_t)row*H);
        const float4* wh = (const float4*)(whh + (size_t)row*H);
        float ax=0.f, ah=0.f;
        for (int k4=0;k4<H/4;++k4){
            float4 a = wi[k4], c = wh[k4];
            ax += a.x*xs[4*k4] + a.y*xs[4*k4+1] + a.z*xs[4*k4+2] + a.w*xs[4*k4+3];
            ah += c.x*hs[4*k4] + c.y*hs[4*k4+1] + c.z*hs[4*k4+2] + c.w*hs[4*k4+3];
        }
        gx[gi] = ax + bih[row];
        gh[gi] = ah + bhh[row];
    }
    float r = sigmoidf_(gx[0]+gh[0]);
    float z = sigmoidf_(gx[1]+gh[1]);
    float n = tanhf(gx[2] + r*gh[2]);
    float hv = (1.f-z)*n + z*hs[t];
    hnew[b*H+t] = hv;
    out_hh[b*H+t] = hv;
}

// ---- Kernel 2: broadcast-half biases ----
__global__ __launch_bounds__(512) void k_dbias(const float* __restrict__ hnew,
    const float* __restrict__ tgt, const float* __restrict__ sem,
    const float* __restrict__ encW, const float* __restrict__ tgtW,
    const float* __restrict__ ptrW,
    float* __restrict__ d_enc, float* __restrict__ d_tgt, float* __restrict__ d_se)
{
    __shared__ float a[H], c[H], s[H];
    int b = blockIdx.x, t = threadIdx.x;
    a[t] = hnew[b*H+t]; c[t] = tgt[b*H+t]; s[t] = sem[b*H+t];
    __syncthreads();
    const float4* we = (const float4*)(encW + (size_t)t*(2*H) + H);
    const float4* wt = (const float4*)(tgtW + (size_t)t*(2*H) + H);
    const float4* wp = (const float4*)(ptrW + (size_t)t*(3*H) + 2*H);
    float ae=0.f, at=0.f, as2=0.f;
    for (int k4=0;k4<H/4;++k4){
        float4 v;
        v = we[k4]; ae  += v.x*a[4*k4]+v.y*a[4*k4+1]+v.z*a[4*k4+2]+v.w*a[4*k4+3];
        v = wt[k4]; at  += v.x*c[4*k4]+v.y*c[4*k4+1]+v.z*c[4*k4+2]+v.w*c[4*k4+3];
        v = wp[k4]; as2 += v.x*s[4*k4]+v.y*s[4*k4+1]+v.z*s[4*k4+2]+v.w*s[4*k4+3];
    }
    d_enc[b*H+t]=ae; d_tgt[b*H+t]=at; d_se[b*H+t]=as2;
}

// ---- Kernel 3: MFMA enc+tgt attention scores ----
// grid: b(128) x nt(4) x ht(8); ht<4 -> enc h-tile, else tgt.
// Block tile 128n x 128h, BK=64. A staged fp32->bf16 inline; W pre-cast bf16.
__global__ __launch_bounds__(256) void k_scores_mfma(
    const float* __restrict__ A, const unsigned short* __restrict__ We,
    const unsigned short* __restrict__ Wt,
    const float* __restrict__ d_enc, const float* __restrict__ d_tgt,
    const float* __restrict__ enc_v, const float* __restrict__ tgt_v,
    float* __restrict__ sc_e, float* __restrict__ sc_t)
{
    __shared__ __align__(16) unsigned short As[128*64];
    __shared__ __align__(16) unsigned short Bs[128*64];
    int blk = blockIdx.x;
    int b = blk >> 5; int rr = blk & 31; int nt = rr >> 3; int ht = rr & 7;
    int n0 = nt*128;
    bool is_tgt = ht >= 4;
    int hb = (ht & 3)*128;
    const unsigned short* W = is_tgt ? Wt : We;
    const float* dv = is_tgt ? d_tgt : d_enc;
    const float* vv = is_tgt ? tgt_v : enc_v;
    float* out = is_tgt ? sc_t : sc_e;

    int t = threadIdx.x;
    int lane = t & 63, wave = t >> 6;
    int wy = wave >> 1, wx = wave & 1;
    int li = lane & 15, quad = lane >> 4;

    floatx4 acc[4][4];
    #pragma unroll
    for (int i=0;i<4;++i)
      #pragma unroll
      for (int j=0;j<4;++j) acc[i][j] = (floatx4)(0.0f);

    const float* Abase = A + ((size_t)(b*N + n0))*H;
    const unsigned short* Wbase = W + (size_t)hb*H;

    for (int kt=0; kt<8; ++kt){
        int k0 = kt*64;
        // stage A: fp32 -> bf16, XOR-swizzled 16B blocks
        #pragma unroll
        for (int c=0;c<4;++c){
            int idx = c*256 + t;
            int row = idx >> 3, kb = idx & 7;
            const float* src = Abase + (size_t)row*H + k0 + kb*8;
            float4 lo = *(const float4*)src;
            float4 hi = *(const float4*)(src+4);
            uint4 p;
            p.x = pk2(lo.x, lo.y); p.y = pk2(lo.z, lo.w);
            p.z = pk2(hi.x, hi.y); p.w = pk2(hi.z, hi.w);
            *(uint4*)&As[row*64 + ((kb ^ (row&7))*8)] = p;
        }
        // stage B: bf16 copy, swizzled
        #pragma unroll
        for (int c=0;c<4;++c){
            int idx = c*256 + t;
            int row = idx >> 3, kb = idx & 7;
            uint4 v = *(const uint4*)(Wbase + (size_t)row*H + k0 + kb*8);
            *(uint4*)&Bs[row*64 + ((kb ^ (row&7))*8)] = v;
        }
        __syncthreads();
        #pragma unroll
        for (int ks=0;ks<2;++ks){
            short8 af[4], bg[4];
            #pragma unroll
            for (int i=0;i<4;++i){
                int m = wy*64 + i*16 + li;
                int kb = (ks*4 + quad) ^ (m&7);
                af[i] = *(const short8*)&As[m*64 + kb*8];
            }
            #pragma unroll
            for (int j=0;j<4;++j){
                int h = wx*64 + j*16 + li;
                int kb = (ks*4 + quad) ^ (h&7);
                bg[j] = *(const short8*)&Bs[h*64 + kb*8];
            }
            #pragma unroll
            for (int i=0;i<4;++i)
              #pragma unroll
              for (int j=0;j<4;++j)
                acc[i][j] = __builtin_amdgcn_mfma_f32_16x16x32_bf16(af[i], bg[j], acc[i][j], 0,0,0);
        }
        __syncthreads();
    }
    // epilogue: sum_h v[h]*tanh(S + d[b,h]) -> per-n atomic
    float nsum[4][4];
    #pragma unroll
    for (int i=0;i<4;++i){ nsum[i][0]=0.f;nsum[i][1]=0.f;nsum[i][2]=0.f;nsum[i][3]=0.f; }
    #pragma unroll
    for (int j=0;j<4;++j){
        int hm = hb + wx*64 + j*16 + li;
        float dj = dv[b*H + hm];
        float vj = vv[hm];
        #pragma unroll
        for (int i=0;i<4;++i)
          #pragma unroll
          for (int rg=0;rg<4;++rg)
            nsum[i][rg] += vj * fast_tanh(acc[i][j][rg] + dj);
    }
    #pragma unroll
    for (int off=1; off<16; off<<=1)
      #pragma unroll
      for (int i=0;i<4;++i)
        #pragma unroll
        for (int rg=0;rg<4;++rg)
          nsum[i][rg] += __shfl_xor(nsum[i][rg], off);
    if (li==0){
        #pragma unroll
        for (int i=0;i<4;++i)
          #pragma unroll
          for (int rg=0;rg<4;++rg)
            atomicAdd(&out[b*N + n0 + wy*64 + i*16 + quad*4 + rg], nsum[i][rg]);
    }
}

// ---------------- Kernel 4: softmax both score rows ----------------
__global__ __launch_bounds__(256) void k_softmax(const float* __restrict__ sc_e,
    const float* __restrict__ sc_t, float* __restrict__ w_e, float* __restrict__ w_t)
{
    __shared__ float buf[256];
    int b = blockIdx.x, t = threadIdx.x;
    float x0 = sc_e[b*N+t], x1 = sc_e[b*N+t+256];
    float m = fmaxf(x0,x1);
    buf[t]=m; __syncthreads();
    for (int s2=128;s2>0;s2>>=1){ if(t<s2) buf[t]=fmaxf(buf[t],buf[t+s2]); __syncthreads(); }
    m = buf[0]; __syncthreads();
    float e0 = __expf(x0-m), e1 = __expf(x1-m);
    buf[t]=e0+e1; __syncthreads();
    for (int s2=128;s2>0;s2>>=1){ if(t<s2) buf[t]+=buf[t+s2]; __syncthreads(); }
    float inv = 1.0f/buf[0]; __syncthreads();
    w_e[b*N+t]=e0*inv; w_e[b*N+t+256]=e1*inv;
    x0 = sc_t[b*N+t]; x1 = sc_t[b*N+t+256];
    m = fmaxf(x0,x1);
    buf[t]=m; __syncthreads();
    for (int s2=128;s2>0;s2>>=1){ if(t<s2) buf[t]=fmaxf(buf[t],buf[t+s2]); __syncthreads(); }
    m = buf[0]; __syncthreads();
    e0 = __expf(x0-m); e1 = __expf(x1-m);
    buf[t]=e0+e1; __syncthreads();
    for (int s2=128;s2>0;s2>>=1){ if(t<s2) buf[t]+=buf[t+s2]; __syncthreads(); }
    inv = 1.0f/buf[0];
    w_t[b*N+t]=e0*inv; w_t[b*N+t+256]=e1*inv;
}

// ---------------- Kernel 5: context = attn @ static ----------------
__global__ __launch_bounds__(256) void k_context(const float* __restrict__ A,
    const float* __restrict__ w_e, const float* __restrict__ w_t,
    float* __restrict__ ctx, float* __restrict__ ctxt)
{
    __shared__ float we[128], wt[128];
    int b = blockIdx.x >> 2, c = blockIdx.x & 3, t = threadIdx.x;
    int n0 = c*128;
    if (t < 128){ we[t]=w_e[b*N+n0+t]; wt[t]=w_t[b*N+n0+t]; }
    __syncthreads();
    float ae0=0.f, ae1=0.f, at0=0.f, at1=0.f;
    for (int n=0;n<128;++n){
        const float* ar = A + (size_t)(b*N + n0 + n)*H;
        float a0 = ar[t], a1 = ar[t+256];
        ae0 += we[n]*a0; ae1 += we[n]*a1;
        at0 += wt[n]*a0; at1 += wt[n]*a1;
    }
    atomicAdd(&ctx[b*H+t],      ae0); atomicAdd(&ctx[b*H+t+256],  ae1);
    atomicAdd(&ctxt[b*H+t],     at0); atomicAdd(&ctxt[b*H+t+256], at1);
}

// ------- Kernel 6: pointer biases -------
__global__ __launch_bounds__(512) void k_dptr(const float* __restrict__ ctx,
    const float* __restrict__ ctxt, const float* __restrict__ d_se,
    const float* __restrict__ ptrW, float* __restrict__ d_pe, float* __restrict__ d_pt)
{
    __shared__ float cs[H], cts[H];
    int b = blockIdx.x, t = threadIdx.x;
    cs[t]=ctx[b*H+t]; cts[t]=ctxt[b*H+t];
    __syncthreads();
    const float4* wp = (const float4*)(ptrW + (size_t)t*(3*H) + H);
    float ae=0.f, at=0.f;
    for (int k4=0;k4<H/4;++k4){
        float4 v = wp[k4];
        ae += v.x*cs[4*k4]+v.y*cs[4*k4+1]+v.z*cs[4*k4+2]+v.w*cs[4*k4+3];
        at += v.x*cts[4*k4]+v.y*cts[4*k4+1]+v.z*cts[4*k4+2]+v.w*cts[4*k4+3];
    }
    float s0 = d_se[b*H+t];
    d_pe[b*H+t]=ae+s0; d_pt[b*H+t]=at+s0;
}

// ---- Kernel 7: MFMA pointer scores — one S GEMM, two tanh epilogues, out = 5*pe + pt ----
__global__ __launch_bounds__(256) void k_probs_mfma(
    const float* __restrict__ A, const unsigned short* __restrict__ Wp,
    const float* __restrict__ d_pe, const float* __restrict__ d_pt,
    const float* __restrict__ ptr_v, float* __restrict__ probs)
{
    __shared__ __align__(16) unsigned short As[128*64];
    __shared__ __align__(16) unsigned short Bs[128*64];
    int blk = blockIdx.x;
    int b = blk >> 4; int rr = blk & 15; int nt = rr >> 2; int ht = rr & 3;
    int n0 = nt*128, hb = ht*128;

    int t = threadIdx.x;
    int lane = t & 63, wave = t >> 6;
    int wy = wave >> 1, wx = wave & 1;
    int li = lane & 15, quad = lane >> 4;

    floatx4 acc[4][4];
    #pragma unroll
    for (int i=0;i<4;++i)
      #pragma unroll
      for (int j=0;j<4;++j) acc[i][j] = (floatx4)(0.0f);

    const float* Abase = A + ((size_t)(b*N + n0))*H;
    const unsigned short* Wbase = Wp + (size_t)hb*H;

    for (int kt=0; kt<8; ++kt){
        int k0 = kt*64;
        #pragma unroll
        for (int c=0;c<4;++c){
            int idx = c*256 + t;
            int row = idx >> 3, kb = idx & 7;
            const float* src = Abase + (size_t)row*H + k0 + kb*8;
            float4 lo = *(const float4*)src;
            float4 hi = *(const float4*)(src+4);
            uint4 p;
            p.x = pk2(lo.x, lo.y); p.y = pk2(lo.z, lo.w);
            p.z = pk2(hi.x, hi.y); p.w = pk2(hi.z, hi.w);
            *(uint4*)&As[row*64 + ((kb ^ (row&7))*8)] = p;
        }
        #pragma unroll
        for (int c=0;c<4;++c){
            int idx = c*256 + t;
            int row = idx >> 3, kb = idx & 7;
            uint4 v = *(const uint4*)(Wbase + (size_t)row*H + k0 + kb*8);
            *(uint4*)&Bs[row*64 + ((kb ^ (row&7))*8)] = v;
        }
        __syncthreads();
        #pragma unroll
        for (int ks=0;ks<2;++ks){
            short8 af[4], bg[4];
            #pragma unroll
            for (int i=0;i<4;++i){
                int m = wy*64 + i*16 + li;
                int kb = (ks*4 + quad) ^ (m&7);
                af[i] = *(const short8*)&As[m*64 + kb*8];
            }
            #pragma unroll
            for (int j=0;j<4;++j){
                int h = wx*64 + j*16 + li;
                int kb = (ks*4 + quad) ^ (h&7);
                bg[j] = *(const short8*)&Bs[h*64 + kb*8];
            }
            #pragma unroll
            for (int i=0;i<4;++i)
              #pragma unroll
              for (int j=0;j<4;++j)
                acc[i][j] = __builtin_amdgcn_mfma_f32_16x16x32_bf16(af[i], bg[j], acc[i][j], 0,0,0);
        }
        __syncthreads();
    }
    float nsum[4][4];
    #pragma unroll
    for (int i=0;i<4;++i){ nsum[i][0]=0.f;nsum[i][1]=0.f;nsum[i][2]=0.f;nsum[i][3]=0.f; }
    #pragma unroll
    for (int j=0;j<4;++j){
        int hm = hb + wx*64 + j*16 + li;
        float de = d_pe[b*H + hm];
        float dt = d_pt[b*H + hm];
        float vj = ptr_v[hm];
        #pragma unroll
        for (int i=0;i<4;++i)
          #pragma unroll
          for (int rg=0;rg<4;++rg){
            float s = acc[i][j][rg];
            nsum[i][rg] += vj * (5.0f*fast_tanh(s + de) + fast_tanh(s + dt));
          }
    }
    #pragma unroll
    for (int off=1; off<16; off<<=1)
      #pragma unroll
      for (int i=0;i<4;++i)
        #pragma unroll
        for (int rg=0;rg<4;++rg)
          nsum[i][rg] += __shfl_xor(nsum[i][rg], off);
    if (li==0){
        #pragma unroll
        for (int i=0;i<4;++i)
          #pragma unroll
          for (int rg=0;rg<4;++rg)
            atomicAdd(&probs[b*N + n0 + wy*64 + i*16 + quad*4 + rg], nsum[i][rg]);
    }
}

extern "C" void kernel_launch(void* const* d_in, const int* in_sizes, int n_in,
                              void* d_out, int out_size, void* d_ws, size_t ws_size,
                              hipStream_t stream)
{
    (void)in_sizes; (void)n_in; (void)out_size; (void)ws_size;
    const float* A    = (const float*)d_in[0];
    const float* sem  = (const float*)d_in[1];
    const float* dec  = (const float*)d_in[2];
    const float* tgt  = (const float*)d_in[3];
    const float* lhh  = (const float*)d_in[4];
    const float* ptrv = (const float*)d_in[5];
    const float* ptrW = (const float*)d_in[6];
    const float* encv = (const float*)d_in[7];
    const float* encW = (const float*)d_in[8];
    const float* tgtv = (const float*)d_in[9];
    const float* tgtW = (const float*)d_in[10];
    const float* wih  = (const float*)d_in[11];
    const float* whh  = (const float*)d_in[12];
    const float* bih  = (const float*)d_in[13];
    const float* bhh  = (const float*)d_in[14];

    float* probs_out = (float*)d_out;
    float* hh_out    = (float*)d_out + B*N;

    float* ws = (float*)d_ws;
    const int S = B*H;
    float* hnew  = ws;
    float* d_enc = ws + (size_t)S;
    float* d_tgt = ws + (size_t)2*S;
    float* d_se  = ws + (size_t)3*S;
    float* sc_e  = ws + (size_t)4*S;
    float* sc_t  = ws + (size_t)5*S;
    float* ctx   = ws + (size_t)6*S;
    float* ctxt  = ws + (size_t)7*S;
    float* w_e   = ws + (size_t)8*S;
    float* w_t   = ws + (size_t)9*S;
    float* d_pe  = ws + (size_t)10*S;
    float* d_pt  = ws + (size_t)11*S;
    unsigned short* We_bf = (unsigned short*)(ws + (size_t)12*S);
    unsigned short* Wt_bf = We_bf + (size_t)H*H;
    unsigned short* Wp_bf = Wt_bf + (size_t)H*H;

    hipMemsetAsync(sc_e, 0, (size_t)4*S*sizeof(float), stream);
    hipMemsetAsync(probs_out, 0, (size_t)B*N*sizeof(float), stream);

    k_castw<<<3*512, 256, 0, stream>>>(encW, tgtW, ptrW, We_bf, Wt_bf, Wp_bf);
    k_gru<<<B, 512, 0, stream>>>(dec, lhh, wih, whh, bih, bhh, hnew, hh_out);
    k_dbias<<<B, 512, 0, stream>>>(hnew, tgt, sem, encW, tgtW, ptrW, d_enc, d_tgt, d_se);
    k_scores_mfma<<<4096, 256, 0, stream>>>(A, We_bf, Wt_bf, d_enc, d_tgt, encv, tgtv, sc_e, sc_t);
    k_softmax<<<B, 256, 0, stream>>>(sc_e, sc_t, w_e, w_t);
    k_context<<<B*4, 256, 0, stream>>>(A, w_e, w_t, ctx, ctxt);
    k_dptr<<<B, 512, 0, stream>>>(ctx, ctxt, d_se, ptrW, d_pe, d_pt);
    k_probs_mfma<<<2048, 256, 0, stream>>>(A, Wp_bf, d_pe, d_pt, ptrv, probs_out);
}

// Round 3
// 794.923 us; speedup vs baseline: 2.2885x; 1.0379x over previous
//
#include <hip/hip_runtime.h>
#include <math.h>

#define B 128
#define N 512
#define H 512

typedef __attribute__((ext_vector_type(8))) short short8;
typedef __attribute__((ext_vector_type(4))) float floatx4;

__device__ __forceinline__ float sigmoidf_(float x){ return 1.0f/(1.0f+__expf(-x)); }

__device__ __forceinline__ float fast_tanh(float x){
    float t = __expf(-2.0f*fabsf(x));
    float r = __fdividef(1.0f - t, 1.0f + t);
    return copysignf(r, x);
}

// fp32 -> bf16 RNE
__device__ __forceinline__ unsigned f2bf1(float f){
    unsigned u = __float_as_uint(f);
    u += 0x7FFFu + ((u>>16)&1u);
    return u>>16;
}
__device__ __forceinline__ unsigned pk2(float a, float b){
    return f2bf1(a) | (f2bf1(b)<<16);
}

// ---------------- Kernel A: cast static_hidden to bf16 ----------------
__global__ __launch_bounds__(256) void k_castA(const float* __restrict__ A,
    unsigned short* __restrict__ Abf)
{
    size_t i = ((size_t)blockIdx.x*256 + threadIdx.x)*8;
    float4 lo = *(const float4*)&A[i];
    float4 hi = *(const float4*)&A[i+4];
    uint4 p;
    p.x = pk2(lo.x,lo.y); p.y = pk2(lo.z,lo.w);
    p.z = pk2(hi.x,hi.y); p.w = pk2(hi.z,hi.w);
    *(uint4*)&Abf[i] = p;
}

// ---------------- Kernel 0: cast W static-halves to bf16 [h][k] ----------------
__global__ __launch_bounds__(256) void k_castw(const float* __restrict__ encW,
    const float* __restrict__ tgtW, const float* __restrict__ ptrW,
    unsigned short* __restrict__ We, unsigned short* __restrict__ Wt,
    unsigned short* __restrict__ Wp)
{
    int blk = blockIdx.x; int mat = blk >> 9; int row = blk & 511; int t = threadIdx.x;
    const float* src; unsigned short* dst; int pitch;
    if (mat==0){ src=encW; dst=We; pitch=2*H; }
    else if (mat==1){ src=tgtW; dst=Wt; pitch=2*H; }
    else { src=ptrW; dst=Wp; pitch=3*H; }
    float2 v = *(const float2*)&src[(size_t)row*pitch + 2*t];
    *(unsigned*)&dst[(size_t)row*H + 2*t] = pk2(v.x, v.y);
}

// ---------------- Kernel 1: GRU step, 4 batches per block ----------------
__global__ __launch_bounds__(512) void k_gru4(const float* __restrict__ dec,
    const float* __restrict__ lhh, const float* __restrict__ wih,
    const float* __restrict__ whh, const float* __restrict__ bih,
    const float* __restrict__ bhh, float* __restrict__ hnew,
    float* __restrict__ out_hh)
{
    __shared__ float xs[4][H], hs[4][H];
    int b0 = blockIdx.x*4, t = threadIdx.x;
    #pragma unroll
    for (int bb=0;bb<4;++bb){ xs[bb][t]=dec[(b0+bb)*H+t]; hs[bb][t]=lhh[(b0+bb)*H+t]; }
    __syncthreads();
    float gx[3][4], gh[3][4];
    #pragma unroll
    for (int gi=0; gi<3; ++gi){
        int row = gi*H + t;
        const float4* wi = (const float4*)(wih + (size_t)row*H);
        const float4* wh = (const float4*)(whh + (size_t)row*H);
        float ax[4]={0.f,0.f,0.f,0.f}, ah[4]={0.f,0.f,0.f,0.f};
        for (int k4=0;k4<H/4;++k4){
            float4 a = wi[k4], c = wh[k4];
            #pragma unroll
            for (int bb=0;bb<4;++bb){
                float4 xv = *(const float4*)&xs[bb][k4*4];
                float4 hv = *(const float4*)&hs[bb][k4*4];
                ax[bb] += a.x*xv.x + a.y*xv.y + a.z*xv.z + a.w*xv.w;
                ah[bb] += c.x*hv.x + c.y*hv.y + c.z*hv.z + c.w*hv.w;
            }
        }
        float bi = bih[row], bh = bhh[row];
        #pragma unroll
        for (int bb=0;bb<4;++bb){ gx[gi][bb]=ax[bb]+bi; gh[gi][bb]=ah[bb]+bh; }
    }
    #pragma unroll
    for (int bb=0;bb<4;++bb){
        float r = sigmoidf_(gx[0][bb]+gh[0][bb]);
        float z = sigmoidf_(gx[1][bb]+gh[1][bb]);
        float nn = tanhf(gx[2][bb] + r*gh[2][bb]);
        float hv = (1.f-z)*nn + z*hs[bb][t];
        hnew[(b0+bb)*H+t] = hv;
        out_hh[(b0+bb)*H+t] = hv;
    }
}

// ---- Kernel 2: broadcast-half biases, 4 batches per block ----
__global__ __launch_bounds__(512) void k_dbias4(const float* __restrict__ hnew,
    const float* __restrict__ tgt, const float* __restrict__ sem,
    const float* __restrict__ encW, const float* __restrict__ tgtW,
    const float* __restrict__ ptrW,
    float* __restrict__ d_enc, float* __restrict__ d_tgt, float* __restrict__ d_se)
{
    __shared__ float a[4][H], c[4][H], s[4][H];
    int b0 = blockIdx.x*4, t = threadIdx.x;
    #pragma unroll
    for (int bb=0;bb<4;++bb){
        a[bb][t]=hnew[(b0+bb)*H+t]; c[bb][t]=tgt[(b0+bb)*H+t]; s[bb][t]=sem[(b0+bb)*H+t];
    }
    __syncthreads();
    const float4* we = (const float4*)(encW + (size_t)t*(2*H) + H);
    const float4* wt = (const float4*)(tgtW + (size_t)t*(2*H) + H);
    const float4* wp = (const float4*)(ptrW + (size_t)t*(3*H) + 2*H);
    float ae[4]={0.f,0.f,0.f,0.f}, at4[4]={0.f,0.f,0.f,0.f}, as2[4]={0.f,0.f,0.f,0.f};
    for (int k4=0;k4<H/4;++k4){
        float4 v;
        v = we[k4];
        #pragma unroll
        for (int bb=0;bb<4;++bb){
            float4 xv = *(const float4*)&a[bb][k4*4];
            ae[bb] += v.x*xv.x+v.y*xv.y+v.z*xv.z+v.w*xv.w;
        }
        v = wt[k4];
        #pragma unroll
        for (int bb=0;bb<4;++bb){
            float4 xv = *(const float4*)&c[bb][k4*4];
            at4[bb] += v.x*xv.x+v.y*xv.y+v.z*xv.z+v.w*xv.w;
        }
        v = wp[k4];
        #pragma unroll
        for (int bb=0;bb<4;++bb){
            float4 xv = *(const float4*)&s[bb][k4*4];
            as2[bb] += v.x*xv.x+v.y*xv.y+v.z*xv.z+v.w*xv.w;
        }
    }
    #pragma unroll
    for (int bb=0;bb<4;++bb){
        d_enc[(b0+bb)*H+t]=ae[bb]; d_tgt[(b0+bb)*H+t]=at4[bb]; d_se[(b0+bb)*H+t]=as2[bb];
    }
}

// ---- Kernel 3: fused enc+tgt MFMA scores. Block = (b, nt, ht), 128n x 128h x 2 matrices ----
template<bool BF16A>
__global__ __launch_bounds__(256,2) void k_scores_fused(
    const float* __restrict__ Af, const unsigned short* __restrict__ Abf,
    const unsigned short* __restrict__ We, const unsigned short* __restrict__ Wt,
    const float* __restrict__ d_enc, const float* __restrict__ d_tgt,
    const float* __restrict__ enc_v, const float* __restrict__ tgt_v,
    float* __restrict__ sc_e, float* __restrict__ sc_t)
{
    __shared__ __align__(16) unsigned short As[128*64];
    __shared__ __align__(16) unsigned short Be[128*64];
    __shared__ __align__(16) unsigned short Bt[128*64];
    int blk = blockIdx.x;
    int b = blk >> 4; int nt = (blk >> 2) & 3; int ht = blk & 3;
    int n0 = nt*128, hb = ht*128;
    int t = threadIdx.x;
    int lane = t & 63, wave = t >> 6;
    int wy = wave >> 1, wx = wave & 1;
    int li = lane & 15, quad = lane >> 4;

    floatx4 acc_e[4][4], acc_t[4][4];
    #pragma unroll
    for (int i=0;i<4;++i)
      #pragma unroll
      for (int j=0;j<4;++j){ acc_e[i][j]=(floatx4)(0.0f); acc_t[i][j]=(floatx4)(0.0f); }

    for (int kt=0; kt<8; ++kt){
        int k0 = kt*64;
        #pragma unroll
        for (int c=0;c<4;++c){
            int idx = c*256 + t;
            int row = idx >> 3, kb = idx & 7;
            if constexpr (BF16A){
                uint4 v = *(const uint4*)&Abf[(size_t)(b*N+n0+row)*H + k0 + kb*8];
                *(uint4*)&As[row*64 + ((kb ^ (row&7))*8)] = v;
            } else {
                const float* src = Af + (size_t)(b*N+n0+row)*H + k0 + kb*8;
                float4 lo = *(const float4*)src;
                float4 hi = *(const float4*)(src+4);
                uint4 p;
                p.x = pk2(lo.x,lo.y); p.y = pk2(lo.z,lo.w);
                p.z = pk2(hi.x,hi.y); p.w = pk2(hi.z,hi.w);
                *(uint4*)&As[row*64 + ((kb ^ (row&7))*8)] = p;
            }
        }
        #pragma unroll
        for (int c=0;c<4;++c){
            int idx = c*256 + t;
            int row = idx >> 3, kb = idx & 7;
            uint4 v = *(const uint4*)&We[(size_t)(hb+row)*H + k0 + kb*8];
            *(uint4*)&Be[row*64 + ((kb ^ (row&7))*8)] = v;
            uint4 w = *(const uint4*)&Wt[(size_t)(hb+row)*H + k0 + kb*8];
            *(uint4*)&Bt[row*64 + ((kb ^ (row&7))*8)] = w;
        }
        __syncthreads();
        #pragma unroll
        for (int ks=0;ks<2;++ks){
            short8 af[4], be[4], bt[4];
            #pragma unroll
            for (int i=0;i<4;++i){
                int m = wy*64 + i*16 + li;
                int kb = (ks*4 + quad) ^ (m&7);
                af[i] = *(const short8*)&As[m*64 + kb*8];
            }
            #pragma unroll
            for (int j=0;j<4;++j){
                int h = wx*64 + j*16 + li;
                int kb = (ks*4 + quad) ^ (h&7);
                be[j] = *(const short8*)&Be[h*64 + kb*8];
                bt[j] = *(const short8*)&Bt[h*64 + kb*8];
            }
            #pragma unroll
            for (int i=0;i<4;++i)
              #pragma unroll
              for (int j=0;j<4;++j){
                acc_e[i][j] = __builtin_amdgcn_mfma_f32_16x16x32_bf16(af[i], be[j], acc_e[i][j], 0,0,0);
                acc_t[i][j] = __builtin_amdgcn_mfma_f32_16x16x32_bf16(af[i], bt[j], acc_t[i][j], 0,0,0);
              }
        }
        __syncthreads();
    }
    float nse[4][4], nst[4][4];
    #pragma unroll
    for (int i=0;i<4;++i)
      #pragma unroll
      for (int rg=0;rg<4;++rg){ nse[i][rg]=0.f; nst[i][rg]=0.f; }
    #pragma unroll
    for (int j=0;j<4;++j){
        int hm = hb + wx*64 + j*16 + li;
        float dje = d_enc[b*H+hm], vje = enc_v[hm];
        float djt = d_tgt[b*H+hm], vjt = tgt_v[hm];
        #pragma unroll
        for (int i=0;i<4;++i)
          #pragma unroll
          for (int rg=0;rg<4;++rg){
            nse[i][rg] += vje * fast_tanh(acc_e[i][j][rg] + dje);
            nst[i][rg] += vjt * fast_tanh(acc_t[i][j][rg] + djt);
          }
    }
    #pragma unroll
    for (int off=1; off<16; off<<=1)
      #pragma unroll
      for (int i=0;i<4;++i)
        #pragma unroll
        for (int rg=0;rg<4;++rg){
          nse[i][rg] += __shfl_xor(nse[i][rg], off);
          nst[i][rg] += __shfl_xor(nst[i][rg], off);
        }
    if (li==0){
        #pragma unroll
        for (int i=0;i<4;++i)
          #pragma unroll
          for (int rg=0;rg<4;++rg){
            atomicAdd(&sc_e[b*N + n0 + wy*64 + i*16 + quad*4 + rg], nse[i][rg]);
            atomicAdd(&sc_t[b*N + n0 + wy*64 + i*16 + quad*4 + rg], nst[i][rg]);
          }
    }
}

// ---------------- Kernel 4: softmax both score rows ----------------
__global__ __launch_bounds__(256) void k_softmax(const float* __restrict__ sc_e,
    const float* __restrict__ sc_t, float* __restrict__ w_e, float* __restrict__ w_t)
{
    __shared__ float buf[256];
    int b = blockIdx.x, t = threadIdx.x;
    float x0 = sc_e[b*N+t], x1 = sc_e[b*N+t+256];
    float m = fmaxf(x0,x1);
    buf[t]=m; __syncthreads();
    for (int s2=128;s2>0;s2>>=1){ if(t<s2) buf[t]=fmaxf(buf[t],buf[t+s2]); __syncthreads(); }
    m = buf[0]; __syncthreads();
    float e0 = __expf(x0-m), e1 = __expf(x1-m);
    buf[t]=e0+e1; __syncthreads();
    for (int s2=128;s2>0;s2>>=1){ if(t<s2) buf[t]+=buf[t+s2]; __syncthreads(); }
    float inv = 1.0f/buf[0]; __syncthreads();
    w_e[b*N+t]=e0*inv; w_e[b*N+t+256]=e1*inv;
    x0 = sc_t[b*N+t]; x1 = sc_t[b*N+t+256];
    m = fmaxf(x0,x1);
    buf[t]=m; __syncthreads();
    for (int s2=128;s2>0;s2>>=1){ if(t<s2) buf[t]=fmaxf(buf[t],buf[t+s2]); __syncthreads(); }
    m = buf[0]; __syncthreads();
    e0 = __expf(x0-m); e1 = __expf(x1-m);
    buf[t]=e0+e1; __syncthreads();
    for (int s2=128;s2>0;s2>>=1){ if(t<s2) buf[t]+=buf[t+s2]; __syncthreads(); }
    inv = 1.0f/buf[0];
    w_t[b*N+t]=e0*inv; w_t[b*N+t+256]=e1*inv;
}

// ---------------- Kernel 5a: context from bf16 A ----------------
__global__ __launch_bounds__(256) void k_context_bf16(const unsigned short* __restrict__ Abf,
    const float* __restrict__ w_e, const float* __restrict__ w_t,
    float* __restrict__ ctx, float* __restrict__ ctxt)
{
    __shared__ float we[64], wt[64];
    int b = blockIdx.x >> 3, c = blockIdx.x & 7, t = threadIdx.x;
    int n0 = c*64;
    if (t < 64){ we[t]=w_e[b*N+n0+t]; wt[t]=w_t[b*N+n0+t]; }
    __syncthreads();
    float ae0=0.f, ae1=0.f, at0=0.f, at1=0.f;
    for (int n=0;n<64;++n){
        unsigned u = *(const unsigned*)&Abf[(size_t)(b*N+n0+n)*H + 2*t];
        float lo = __uint_as_float(u<<16);
        float hi = __uint_as_float(u & 0xFFFF0000u);
        float e = we[n], g = wt[n];
        ae0 += e*lo; ae1 += e*hi; at0 += g*lo; at1 += g*hi;
    }
    atomicAdd(&ctx[b*H+2*t],   ae0); atomicAdd(&ctx[b*H+2*t+1],  ae1);
    atomicAdd(&ctxt[b*H+2*t],  at0); atomicAdd(&ctxt[b*H+2*t+1], at1);
}

// ---------------- Kernel 5b: context from fp32 A (fallback) ----------------
__global__ __launch_bounds__(256) void k_context(const float* __restrict__ A,
    const float* __restrict__ w_e, const float* __restrict__ w_t,
    float* __restrict__ ctx, float* __restrict__ ctxt)
{
    __shared__ float we[128], wt[128];
    int b = blockIdx.x >> 2, c = blockIdx.x & 3, t = threadIdx.x;
    int n0 = c*128;
    if (t < 128){ we[t]=w_e[b*N+n0+t]; wt[t]=w_t[b*N+n0+t]; }
    __syncthreads();
    float ae0=0.f, ae1=0.f, at0=0.f, at1=0.f;
    for (int n=0;n<128;++n){
        const float* ar = A + (size_t)(b*N + n0 + n)*H;
        float a0 = ar[t], a1 = ar[t+256];
        ae0 += we[n]*a0; ae1 += we[n]*a1;
        at0 += wt[n]*a0; at1 += wt[n]*a1;
    }
    atomicAdd(&ctx[b*H+t],      ae0); atomicAdd(&ctx[b*H+t+256],  ae1);
    atomicAdd(&ctxt[b*H+t],     at0); atomicAdd(&ctxt[b*H+t+256], at1);
}

// ------- Kernel 6: pointer biases, 4 batches per block -------
__global__ __launch_bounds__(512) void k_dptr4(const float* __restrict__ ctx,
    const float* __restrict__ ctxt, const float* __restrict__ d_se,
    const float* __restrict__ ptrW, float* __restrict__ d_pe, float* __restrict__ d_pt)
{
    __shared__ float cs[4][H], cts[4][H];
    int b0 = blockIdx.x*4, t = threadIdx.x;
    #pragma unroll
    for (int bb=0;bb<4;++bb){ cs[bb][t]=ctx[(b0+bb)*H+t]; cts[bb][t]=ctxt[(b0+bb)*H+t]; }
    __syncthreads();
    const float4* wp = (const float4*)(ptrW + (size_t)t*(3*H) + H);
    float ae[4]={0.f,0.f,0.f,0.f}, at4[4]={0.f,0.f,0.f,0.f};
    for (int k4=0;k4<H/4;++k4){
        float4 v = wp[k4];
        #pragma unroll
        for (int bb=0;bb<4;++bb){
            float4 cv  = *(const float4*)&cs[bb][k4*4];
            float4 ctv = *(const float4*)&cts[bb][k4*4];
            ae[bb]  += v.x*cv.x+v.y*cv.y+v.z*cv.z+v.w*cv.w;
            at4[bb] += v.x*ctv.x+v.y*ctv.y+v.z*ctv.z+v.w*ctv.w;
        }
    }
    #pragma unroll
    for (int bb=0;bb<4;++bb){
        float s0 = d_se[(b0+bb)*H+t];
        d_pe[(b0+bb)*H+t]=ae[bb]+s0; d_pt[(b0+bb)*H+t]=at4[bb]+s0;
    }
}

// ---- Kernel 7: MFMA pointer scores — one S GEMM, two tanh epilogues ----
template<bool BF16A>
__global__ __launch_bounds__(256) void k_probs_mfma(
    const float* __restrict__ Af, const unsigned short* __restrict__ Abf,
    const unsigned short* __restrict__ Wp,
    const float* __restrict__ d_pe, const float* __restrict__ d_pt,
    const float* __restrict__ ptr_v, float* __restrict__ probs)
{
    __shared__ __align__(16) unsigned short As[128*64];
    __shared__ __align__(16) unsigned short Bs[128*64];
    int blk = blockIdx.x;
    int b = blk >> 4; int nt = (blk >> 2) & 3; int ht = blk & 3;
    int n0 = nt*128, hb = ht*128;

    int t = threadIdx.x;
    int lane = t & 63, wave = t >> 6;
    int wy = wave >> 1, wx = wave & 1;
    int li = lane & 15, quad = lane >> 4;

    floatx4 acc[4][4];
    #pragma unroll
    for (int i=0;i<4;++i)
      #pragma unroll
      for (int j=0;j<4;++j) acc[i][j] = (floatx4)(0.0f);

    for (int kt=0; kt<8; ++kt){
        int k0 = kt*64;
        #pragma unroll
        for (int c=0;c<4;++c){
            int idx = c*256 + t;
            int row = idx >> 3, kb = idx & 7;
            if constexpr (BF16A){
                uint4 v = *(const uint4*)&Abf[(size_t)(b*N+n0+row)*H + k0 + kb*8];
                *(uint4*)&As[row*64 + ((kb ^ (row&7))*8)] = v;
            } else {
                const float* src = Af + (size_t)(b*N+n0+row)*H + k0 + kb*8;
                float4 lo = *(const float4*)src;
                float4 hi = *(const float4*)(src+4);
                uint4 p;
                p.x = pk2(lo.x,lo.y); p.y = pk2(lo.z,lo.w);
                p.z = pk2(hi.x,hi.y); p.w = pk2(hi.z,hi.w);
                *(uint4*)&As[row*64 + ((kb ^ (row&7))*8)] = p;
            }
        }
        #pragma unroll
        for (int c=0;c<4;++c){
            int idx = c*256 + t;
            int row = idx >> 3, kb = idx & 7;
            uint4 v = *(const uint4*)&Wp[(size_t)(hb+row)*H + k0 + kb*8];
            *(uint4*)&Bs[row*64 + ((kb ^ (row&7))*8)] = v;
        }
        __syncthreads();
        #pragma unroll
        for (int ks=0;ks<2;++ks){
            short8 af[4], bg[4];
            #pragma unroll
            for (int i=0;i<4;++i){
                int m = wy*64 + i*16 + li;
                int kb = (ks*4 + quad) ^ (m&7);
                af[i] = *(const short8*)&As[m*64 + kb*8];
            }
            #pragma unroll
            for (int j=0;j<4;++j){
                int h = wx*64 + j*16 + li;
                int kb = (ks*4 + quad) ^ (h&7);
                bg[j] = *(const short8*)&Bs[h*64 + kb*8];
            }
            #pragma unroll
            for (int i=0;i<4;++i)
              #pragma unroll
              for (int j=0;j<4;++j)
                acc[i][j] = __builtin_amdgcn_mfma_f32_16x16x32_bf16(af[i], bg[j], acc[i][j], 0,0,0);
        }
        __syncthreads();
    }
    float nsum[4][4];
    #pragma unroll
    for (int i=0;i<4;++i){ nsum[i][0]=0.f;nsum[i][1]=0.f;nsum[i][2]=0.f;nsum[i][3]=0.f; }
    #pragma unroll
    for (int j=0;j<4;++j){
        int hm = hb + wx*64 + j*16 + li;
        float de = d_pe[b*H + hm];
        float dt = d_pt[b*H + hm];
        float vj = ptr_v[hm];
        #pragma unroll
        for (int i=0;i<4;++i)
          #pragma unroll
          for (int rg=0;rg<4;++rg){
            float s = acc[i][j][rg];
            nsum[i][rg] += vj * (5.0f*fast_tanh(s + de) + fast_tanh(s + dt));
          }
    }
    #pragma unroll
    for (int off=1; off<16; off<<=1)
      #pragma unroll
      for (int i=0;i<4;++i)
        #pragma unroll
        for (int rg=0;rg<4;++rg)
          nsum[i][rg] += __shfl_xor(nsum[i][rg], off);
    if (li==0){
        #pragma unroll
        for (int i=0;i<4;++i)
          #pragma unroll
          for (int rg=0;rg<4;++rg)
            atomicAdd(&probs[b*N + n0 + wy*64 + i*16 + quad*4 + rg], nsum[i][rg]);
    }
}

extern "C" void kernel_launch(void* const* d_in, const int* in_sizes, int n_in,
                              void* d_out, int out_size, void* d_ws, size_t ws_size,
                              hipStream_t stream)
{
    (void)in_sizes; (void)n_in; (void)out_size;
    const float* A    = (const float*)d_in[0];
    const float* sem  = (const float*)d_in[1];
    const float* dec  = (const float*)d_in[2];
    const float* tgt  = (const float*)d_in[3];
    const float* lhh  = (const float*)d_in[4];
    const float* ptrv = (const float*)d_in[5];
    const float* ptrW = (const float*)d_in[6];
    const float* encv = (const float*)d_in[7];
    const float* encW = (const float*)d_in[8];
    const float* tgtv = (const float*)d_in[9];
    const float* tgtW = (const float*)d_in[10];
    const float* wih  = (const float*)d_in[11];
    const float* whh  = (const float*)d_in[12];
    const float* bih  = (const float*)d_in[13];
    const float* bhh  = (const float*)d_in[14];

    float* probs_out = (float*)d_out;
    float* hh_out    = (float*)d_out + B*N;

    float* ws = (float*)d_ws;
    const size_t S = (size_t)B*H;
    float* hnew  = ws;
    float* d_enc = ws + S;
    float* d_tgt = ws + 2*S;
    float* d_se  = ws + 3*S;
    float* sc_e  = ws + 4*S;
    float* sc_t  = ws + 5*S;
    float* ctx   = ws + 6*S;
    float* ctxt  = ws + 7*S;
    float* w_e   = ws + 8*S;
    float* w_t   = ws + 9*S;
    float* d_pe  = ws + 10*S;
    float* d_pt  = ws + 11*S;
    unsigned short* We_bf = (unsigned short*)(ws + 12*S);
    unsigned short* Wt_bf = We_bf + (size_t)H*H;
    unsigned short* Wp_bf = Wt_bf + (size_t)H*H;
    unsigned short* Abf   = Wp_bf + (size_t)H*H;

    const size_t need = 12*S*sizeof(float) + 3*(size_t)H*H*2 + (size_t)B*N*H*2;
    const bool big = ws_size >= need;

    hipMemsetAsync(sc_e, 0, 4*S*sizeof(float), stream);   // sc_e, sc_t, ctx, ctxt
    hipMemsetAsync(probs_out, 0, (size_t)B*N*sizeof(float), stream);

    k_castw<<<3*512, 256, 0, stream>>>(encW, tgtW, ptrW, We_bf, Wt_bf, Wp_bf);
    if (big) k_castA<<<(B*N*H)/(256*8), 256, 0, stream>>>(A, Abf);
    k_gru4<<<B/4, 512, 0, stream>>>(dec, lhh, wih, whh, bih, bhh, hnew, hh_out);
    k_dbias4<<<B/4, 512, 0, stream>>>(hnew, tgt, sem, encW, tgtW, ptrW, d_enc, d_tgt, d_se);
    if (big)
        k_scores_fused<true ><<<2048, 256, 0, stream>>>(A, Abf, We_bf, Wt_bf, d_enc, d_tgt, encv, tgtv, sc_e, sc_t);
    else
        k_scores_fused<false><<<2048, 256, 0, stream>>>(A, Abf, We_bf, Wt_bf, d_enc, d_tgt, encv, tgtv, sc_e, sc_t);
    k_softmax<<<B, 256, 0, stream>>>(sc_e, sc_t, w_e, w_t);
    if (big)
        k_context_bf16<<<B*8, 256, 0, stream>>>(Abf, w_e, w_t, ctx, ctxt);
    else
        k_context<<<B*4, 256, 0, stream>>>(A, w_e, w_t, ctx, ctxt);
    k_dptr4<<<B/4, 512, 0, stream>>>(ctx, ctxt, d_se, ptrW, d_pe, d_pt);
    if (big)
        k_probs_mfma<true ><<<2048, 256, 0, stream>>>(A, Abf, Wp_bf, d_pe, d_pt, ptrv, probs_out);
    else
        k_probs_mfma<false><<<2048, 256, 0, stream>>>(A, Abf, Wp_bf, d_pe, d_pt, ptrv, probs_out);
}

// Round 4
// 504.342 us; speedup vs baseline: 3.6071x; 1.5762x over previous
//
#include <hip/hip_runtime.h>
#include <math.h>

#define B 128
#define N 512
#define H 512

typedef __attribute__((ext_vector_type(8))) short short8;
typedef __attribute__((ext_vector_type(4))) float floatx4;

__device__ __forceinline__ float sigmoidf_(float x){ return 1.0f/(1.0f+__expf(-x)); }

__device__ __forceinline__ float fast_tanh(float x){
    float t = __expf(-2.0f*fabsf(x));
    float r = __fdividef(1.0f - t, 1.0f + t);
    return copysignf(r, x);
}

// fp32 -> bf16 RNE
__device__ __forceinline__ unsigned f2bf1(float f){
    unsigned u = __float_as_uint(f);
    u += 0x7FFFu + ((u>>16)&1u);
    return u>>16;
}
__device__ __forceinline__ unsigned pk2(float a, float b){
    return f2bf1(a) | (f2bf1(b)<<16);
}

// ---------------- cast static_hidden to bf16 ----------------
__global__ __launch_bounds__(256) void k_castA(const float* __restrict__ A,
    unsigned short* __restrict__ Abf)
{
    size_t i = ((size_t)blockIdx.x*256 + threadIdx.x)*8;
    float4 lo = *(const float4*)&A[i];
    float4 hi = *(const float4*)&A[i+4];
    uint4 p;
    p.x = pk2(lo.x,lo.y); p.y = pk2(lo.z,lo.w);
    p.z = pk2(hi.x,hi.y); p.w = pk2(hi.z,hi.w);
    *(uint4*)&Abf[i] = p;
}

// ------- cast ALL weight chunks to bf16 [row][k] k-contig. grid = 6656 rows -------
__global__ __launch_bounds__(256) void k_castw(
    const float* __restrict__ encW, const float* __restrict__ tgtW,
    const float* __restrict__ ptrW, const float* __restrict__ wih,
    const float* __restrict__ whh,
    unsigned short* __restrict__ We_s, unsigned short* __restrict__ Wt_s,
    unsigned short* __restrict__ Wp_s, unsigned short* __restrict__ We_d,
    unsigned short* __restrict__ Wt_d, unsigned short* __restrict__ Wp_c,
    unsigned short* __restrict__ Wp_e, unsigned short* __restrict__ Wih_b,
    unsigned short* __restrict__ Whh_b)
{
    int r = blockIdx.x, t = threadIdx.x;
    const float* src; unsigned short* dst; int pitch, off, row;
    if (r < 512)      { src=encW; dst=We_s; pitch=2*H; off=0;   row=r; }
    else if (r<1024)  { src=tgtW; dst=Wt_s; pitch=2*H; off=0;   row=r-512; }
    else if (r<1536)  { src=ptrW; dst=Wp_s; pitch=3*H; off=0;   row=r-1024; }
    else if (r<2048)  { src=encW; dst=We_d; pitch=2*H; off=H;   row=r-1536; }
    else if (r<2560)  { src=tgtW; dst=Wt_d; pitch=2*H; off=H;   row=r-2048; }
    else if (r<3072)  { src=ptrW; dst=Wp_c; pitch=3*H; off=H;   row=r-2560; }
    else if (r<3584)  { src=ptrW; dst=Wp_e; pitch=3*H; off=2*H; row=r-3072; }
    else if (r<5120)  { src=wih;  dst=Wih_b;pitch=H;   off=0;   row=r-3584; }
    else              { src=whh;  dst=Whh_b;pitch=H;   off=0;   row=r-5120; }
    float2 v = *(const float2*)&src[(size_t)row*pitch + off + 2*t];
    *(unsigned*)&dst[(size_t)row*H + 2*t] = pk2(v.x, v.y);
}

// ---------------- cast small activations to bf16 (grid 128) ----------------
__global__ __launch_bounds__(256) void k_castX(const float* __restrict__ dec,
    const float* __restrict__ lhh, const float* __restrict__ tgt,
    const float* __restrict__ sem,
    unsigned short* __restrict__ Xbf, unsigned short* __restrict__ Hbf,
    unsigned short* __restrict__ Tbf, unsigned short* __restrict__ Sbf)
{
    int blk = blockIdx.x; int mat = blk >> 5;
    const float* src = mat==0?dec : mat==1?lhh : mat==2?tgt : sem;
    unsigned short* dst = mat==0?Xbf : mat==1?Hbf : mat==2?Tbf : Sbf;
    size_t i = ((size_t)(blk&31)*256 + threadIdx.x)*8;
    float4 lo = *(const float4*)&src[i];
    float4 hi = *(const float4*)&src[i+4];
    uint4 p;
    p.x = pk2(lo.x,lo.y); p.y = pk2(lo.z,lo.w);
    p.z = pk2(hi.x,hi.y); p.w = pk2(hi.z,hi.w);
    *(uint4*)&dst[i] = p;
}

__global__ __launch_bounds__(256) void k_castctx(const float* __restrict__ ctx,
    const float* __restrict__ ctxt,
    unsigned short* __restrict__ CXbf, unsigned short* __restrict__ CTbf)
{
    int blk = blockIdx.x; int mat = blk >> 5;
    const float* src = mat ? ctxt : ctx;
    unsigned short* dst = mat ? CTbf : CXbf;
    size_t i = ((size_t)(blk&31)*256 + threadIdx.x)*8;
    float4 lo = *(const float4*)&src[i];
    float4 hi = *(const float4*)&src[i+4];
    uint4 p;
    p.x = pk2(lo.x,lo.y); p.y = pk2(lo.z,lo.w);
    p.z = pk2(hi.x,hi.y); p.w = pk2(hi.z,hi.w);
    *(uint4*)&dst[i] = p;
}

// ---------------- shared 128x128x512 bf16 MFMA tile: C = A @ B^T ----------------
__device__ __forceinline__ void gemm128_tile(
    const unsigned short* __restrict__ Ab,   // 128 rows x 512, row-major bf16
    const unsigned short* __restrict__ Bb,   // 128 rows x 512, row-major bf16
    float* __restrict__ C, int ldc)          // C[m][n]
{
    __shared__ __align__(16) unsigned short As[128*64];
    __shared__ __align__(16) unsigned short Bs[128*64];
    int t = threadIdx.x;
    int lane = t & 63, wave = t >> 6;
    int wy = wave >> 1, wx = wave & 1;
    int li = lane & 15, quad = lane >> 4;

    floatx4 acc[4][4];
    #pragma unroll
    for (int i=0;i<4;++i)
      #pragma unroll
      for (int j=0;j<4;++j) acc[i][j] = (floatx4)(0.0f);

    for (int kt=0; kt<8; ++kt){
        int k0 = kt*64;
        #pragma unroll
        for (int c=0;c<4;++c){
            int idx = c*256 + t;
            int row = idx >> 3, kb = idx & 7;
            uint4 va = *(const uint4*)&Ab[(size_t)row*512 + k0 + kb*8];
            *(uint4*)&As[row*64 + ((kb ^ (row&7))*8)] = va;
            uint4 vb = *(const uint4*)&Bb[(size_t)row*512 + k0 + kb*8];
            *(uint4*)&Bs[row*64 + ((kb ^ (row&7))*8)] = vb;
        }
        __syncthreads();
        #pragma unroll
        for (int ks=0;ks<2;++ks){
            short8 af[4], bg[4];
            #pragma unroll
            for (int i=0;i<4;++i){
                int m = wy*64 + i*16 + li;
                int kb = (ks*4 + quad) ^ (m&7);
                af[i] = *(const short8*)&As[m*64 + kb*8];
            }
            #pragma unroll
            for (int j=0;j<4;++j){
                int h = wx*64 + j*16 + li;
                int kb = (ks*4 + quad) ^ (h&7);
                bg[j] = *(const short8*)&Bs[h*64 + kb*8];
            }
            #pragma unroll
            for (int i=0;i<4;++i)
              #pragma unroll
              for (int j=0;j<4;++j)
                acc[i][j] = __builtin_amdgcn_mfma_f32_16x16x32_bf16(af[i], bg[j], acc[i][j], 0,0,0);
        }
        __syncthreads();
    }
    #pragma unroll
    for (int i=0;i<4;++i)
      #pragma unroll
      for (int j=0;j<4;++j)
        #pragma unroll
        for (int rg=0;rg<4;++rg){
            int m = wy*64 + i*16 + quad*4 + rg;
            int n = wx*64 + j*16 + li;
            C[(size_t)m*ldc + n] = acc[i][j][rg];
        }
}

// ---- GRU gates GEMM: gx = X@Wih^T (128x1536), gh = H@Whh^T (grid 24) ----
__global__ __launch_bounds__(256,2) void k_gru_gemm(
    const unsigned short* __restrict__ Xbf, const unsigned short* __restrict__ Hbf,
    const unsigned short* __restrict__ Wih_b, const unsigned short* __restrict__ Whh_b,
    float* __restrict__ gx, float* __restrict__ gh)
{
    int blk = blockIdx.x;
    int mat = blk / 12, nt = blk % 12;
    const unsigned short* Ab = mat ? Hbf : Xbf;
    const unsigned short* Bb = (mat ? Whh_b : Wih_b) + (size_t)nt*128*512;
    float* C = (mat ? gh : gx) + nt*128;
    gemm128_tile(Ab, Bb, C, 3*H);
}

// ---- GRU elementwise gates (biases added here) ----
__global__ __launch_bounds__(256) void k_gru_gate(const float* __restrict__ gx,
    const float* __restrict__ gh, const float* __restrict__ lhh,
    const float* __restrict__ bih, const float* __restrict__ bhh,
    float* __restrict__ out_hh, unsigned short* __restrict__ hnew_bf)
{
    int idx = blockIdx.x*256 + threadIdx.x;   // 0..65535
    int b = idx >> 9, k = idx & 511;
    const float* gxb = gx + (size_t)b*(3*H);
    const float* ghb = gh + (size_t)b*(3*H);
    float r = sigmoidf_(gxb[k]     + bih[k]     + ghb[k]     + bhh[k]);
    float z = sigmoidf_(gxb[H+k]   + bih[H+k]   + ghb[H+k]   + bhh[H+k]);
    float n = tanhf(gxb[2*H+k] + bih[2*H+k] + r*(ghb[2*H+k] + bhh[2*H+k]));
    float h = (1.f-z)*n + z*lhh[idx];
    out_hh[idx] = h;
    hnew_bf[idx] = (unsigned short)f2bf1(h);
}

// ---- broadcast-half biases GEMM (grid 12) ----
__global__ __launch_bounds__(256,2) void k_bias_gemm(
    const unsigned short* __restrict__ HNbf, const unsigned short* __restrict__ Tbf,
    const unsigned short* __restrict__ Sbf,
    const unsigned short* __restrict__ We_d, const unsigned short* __restrict__ Wt_d,
    const unsigned short* __restrict__ Wp_e,
    float* __restrict__ d_enc, float* __restrict__ d_tgt, float* __restrict__ d_se)
{
    int blk = blockIdx.x;
    int mat = blk >> 2, nt = blk & 3;
    const unsigned short* Ab = mat==0 ? HNbf : mat==1 ? Tbf : Sbf;
    const unsigned short* Bb = (mat==0 ? We_d : mat==1 ? Wt_d : Wp_e) + (size_t)nt*128*512;
    float* C = (mat==0 ? d_enc : mat==1 ? d_tgt : d_se) + nt*128;
    gemm128_tile(Ab, Bb, C, H);
}

// ---- pointer biases GEMM (grid 8): d_pe = ctx@Wp_c^T, d_pt = ctxt@Wp_c^T ----
__global__ __launch_bounds__(256,2) void k_dptr_gemm(
    const unsigned short* __restrict__ CXbf, const unsigned short* __restrict__ CTbf,
    const unsigned short* __restrict__ Wp_c,
    float* __restrict__ d_pe, float* __restrict__ d_pt)
{
    int blk = blockIdx.x;
    int mat = blk >> 2, nt = blk & 3;
    const unsigned short* Ab = mat ? CTbf : CXbf;
    const unsigned short* Bb = Wp_c + (size_t)nt*128*512;
    float* C = (mat ? d_pt : d_pe) + nt*128;
    gemm128_tile(Ab, Bb, C, H);
}

// ---- fused enc+tgt MFMA scores (grid 2048) ----
template<bool BF16A>
__global__ __launch_bounds__(256,2) void k_scores_fused(
    const float* __restrict__ Af, const unsigned short* __restrict__ Abf,
    const unsigned short* __restrict__ We, const unsigned short* __restrict__ Wt,
    const float* __restrict__ d_enc, const float* __restrict__ d_tgt,
    const float* __restrict__ enc_v, const float* __restrict__ tgt_v,
    float* __restrict__ sc_e, float* __restrict__ sc_t)
{
    __shared__ __align__(16) unsigned short As[128*64];
    __shared__ __align__(16) unsigned short Be[128*64];
    __shared__ __align__(16) unsigned short Bt[128*64];
    int blk = blockIdx.x;
    int b = blk >> 4; int nt = (blk >> 2) & 3; int ht = blk & 3;
    int n0 = nt*128, hb = ht*128;
    int t = threadIdx.x;
    int lane = t & 63, wave = t >> 6;
    int wy = wave >> 1, wx = wave & 1;
    int li = lane & 15, quad = lane >> 4;

    floatx4 acc_e[4][4], acc_t[4][4];
    #pragma unroll
    for (int i=0;i<4;++i)
      #pragma unroll
      for (int j=0;j<4;++j){ acc_e[i][j]=(floatx4)(0.0f); acc_t[i][j]=(floatx4)(0.0f); }

    for (int kt=0; kt<8; ++kt){
        int k0 = kt*64;
        #pragma unroll
        for (int c=0;c<4;++c){
            int idx = c*256 + t;
            int row = idx >> 3, kb = idx & 7;
            if constexpr (BF16A){
                uint4 v = *(const uint4*)&Abf[(size_t)(b*N+n0+row)*H + k0 + kb*8];
                *(uint4*)&As[row*64 + ((kb ^ (row&7))*8)] = v;
            } else {
                const float* src = Af + (size_t)(b*N+n0+row)*H + k0 + kb*8;
                float4 lo = *(const float4*)src;
                float4 hi = *(const float4*)(src+4);
                uint4 p;
                p.x = pk2(lo.x,lo.y); p.y = pk2(lo.z,lo.w);
                p.z = pk2(hi.x,hi.y); p.w = pk2(hi.z,hi.w);
                *(uint4*)&As[row*64 + ((kb ^ (row&7))*8)] = p;
            }
        }
        #pragma unroll
        for (int c=0;c<4;++c){
            int idx = c*256 + t;
            int row = idx >> 3, kb = idx & 7;
            uint4 v = *(const uint4*)&We[(size_t)(hb+row)*H + k0 + kb*8];
            *(uint4*)&Be[row*64 + ((kb ^ (row&7))*8)] = v;
            uint4 w = *(const uint4*)&Wt[(size_t)(hb+row)*H + k0 + kb*8];
            *(uint4*)&Bt[row*64 + ((kb ^ (row&7))*8)] = w;
        }
        __syncthreads();
        #pragma unroll
        for (int ks=0;ks<2;++ks){
            short8 af[4], be[4], bt[4];
            #pragma unroll
            for (int i=0;i<4;++i){
                int m = wy*64 + i*16 + li;
                int kb = (ks*4 + quad) ^ (m&7);
                af[i] = *(const short8*)&As[m*64 + kb*8];
            }
            #pragma unroll
            for (int j=0;j<4;++j){
                int h = wx*64 + j*16 + li;
                int kb = (ks*4 + quad) ^ (h&7);
                be[j] = *(const short8*)&Be[h*64 + kb*8];
                bt[j] = *(const short8*)&Bt[h*64 + kb*8];
            }
            #pragma unroll
            for (int i=0;i<4;++i)
              #pragma unroll
              for (int j=0;j<4;++j){
                acc_e[i][j] = __builtin_amdgcn_mfma_f32_16x16x32_bf16(af[i], be[j], acc_e[i][j], 0,0,0);
                acc_t[i][j] = __builtin_amdgcn_mfma_f32_16x16x32_bf16(af[i], bt[j], acc_t[i][j], 0,0,0);
              }
        }
        __syncthreads();
    }
    float nse[4][4], nst[4][4];
    #pragma unroll
    for (int i=0;i<4;++i)
      #pragma unroll
      for (int rg=0;rg<4;++rg){ nse[i][rg]=0.f; nst[i][rg]=0.f; }
    #pragma unroll
    for (int j=0;j<4;++j){
        int hm = hb + wx*64 + j*16 + li;
        float dje = d_enc[b*H+hm], vje = enc_v[hm];
        float djt = d_tgt[b*H+hm], vjt = tgt_v[hm];
        #pragma unroll
        for (int i=0;i<4;++i)
          #pragma unroll
          for (int rg=0;rg<4;++rg){
            nse[i][rg] += vje * fast_tanh(acc_e[i][j][rg] + dje);
            nst[i][rg] += vjt * fast_tanh(acc_t[i][j][rg] + djt);
          }
    }
    #pragma unroll
    for (int off=1; off<16; off<<=1)
      #pragma unroll
      for (int i=0;i<4;++i)
        #pragma unroll
        for (int rg=0;rg<4;++rg){
          nse[i][rg] += __shfl_xor(nse[i][rg], off);
          nst[i][rg] += __shfl_xor(nst[i][rg], off);
        }
    if (li==0){
        #pragma unroll
        for (int i=0;i<4;++i)
          #pragma unroll
          for (int rg=0;rg<4;++rg){
            atomicAdd(&sc_e[b*N + n0 + wy*64 + i*16 + quad*4 + rg], nse[i][rg]);
            atomicAdd(&sc_t[b*N + n0 + wy*64 + i*16 + quad*4 + rg], nst[i][rg]);
          }
    }
}

// ---------------- softmax both score rows ----------------
__global__ __launch_bounds__(256) void k_softmax(const float* __restrict__ sc_e,
    const float* __restrict__ sc_t, float* __restrict__ w_e, float* __restrict__ w_t)
{
    __shared__ float buf[256];
    int b = blockIdx.x, t = threadIdx.x;
    float x0 = sc_e[b*N+t], x1 = sc_e[b*N+t+256];
    float m = fmaxf(x0,x1);
    buf[t]=m; __syncthreads();
    for (int s2=128;s2>0;s2>>=1){ if(t<s2) buf[t]=fmaxf(buf[t],buf[t+s2]); __syncthreads(); }
    m = buf[0]; __syncthreads();
    float e0 = __expf(x0-m), e1 = __expf(x1-m);
    buf[t]=e0+e1; __syncthreads();
    for (int s2=128;s2>0;s2>>=1){ if(t<s2) buf[t]+=buf[t+s2]; __syncthreads(); }
    float inv = 1.0f/buf[0]; __syncthreads();
    w_e[b*N+t]=e0*inv; w_e[b*N+t+256]=e1*inv;
    x0 = sc_t[b*N+t]; x1 = sc_t[b*N+t+256];
    m = fmaxf(x0,x1);
    buf[t]=m; __syncthreads();
    for (int s2=128;s2>0;s2>>=1){ if(t<s2) buf[t]=fmaxf(buf[t],buf[t+s2]); __syncthreads(); }
    m = buf[0]; __syncthreads();
    e0 = __expf(x0-m); e1 = __expf(x1-m);
    buf[t]=e0+e1; __syncthreads();
    for (int s2=128;s2>0;s2>>=1){ if(t<s2) buf[t]+=buf[t+s2]; __syncthreads(); }
    inv = 1.0f/buf[0];
    w_t[b*N+t]=e0*inv; w_t[b*N+t+256]=e1*inv;
}

// ---------------- context from bf16 A ----------------
__global__ __launch_bounds__(256) void k_context_bf16(const unsigned short* __restrict__ Abf,
    const float* __restrict__ w_e, const float* __restrict__ w_t,
    float* __restrict__ ctx, float* __restrict__ ctxt)
{
    __shared__ float we[64], wt[64];
    int b = blockIdx.x >> 3, c = blockIdx.x & 7, t = threadIdx.x;
    int n0 = c*64;
    if (t < 64){ we[t]=w_e[b*N+n0+t]; wt[t]=w_t[b*N+n0+t]; }
    __syncthreads();
    float ae0=0.f, ae1=0.f, at0=0.f, at1=0.f;
    for (int n=0;n<64;++n){
        unsigned u = *(const unsigned*)&Abf[(size_t)(b*N+n0+n)*H + 2*t];
        float lo = __uint_as_float(u<<16);
        float hi = __uint_as_float(u & 0xFFFF0000u);
        float e = we[n], g = wt[n];
        ae0 += e*lo; ae1 += e*hi; at0 += g*lo; at1 += g*hi;
    }
    atomicAdd(&ctx[b*H+2*t],   ae0); atomicAdd(&ctx[b*H+2*t+1],  ae1);
    atomicAdd(&ctxt[b*H+2*t],  at0); atomicAdd(&ctxt[b*H+2*t+1], at1);
}

// ---------------- context from fp32 A (fallback) ----------------
__global__ __launch_bounds__(256) void k_context(const float* __restrict__ A,
    const float* __restrict__ w_e, const float* __restrict__ w_t,
    float* __restrict__ ctx, float* __restrict__ ctxt)
{
    __shared__ float we[128], wt[128];
    int b = blockIdx.x >> 2, c = blockIdx.x & 3, t = threadIdx.x;
    int n0 = c*128;
    if (t < 128){ we[t]=w_e[b*N+n0+t]; wt[t]=w_t[b*N+n0+t]; }
    __syncthreads();
    float ae0=0.f, ae1=0.f, at0=0.f, at1=0.f;
    for (int n=0;n<128;++n){
        const float* ar = A + (size_t)(b*N + n0 + n)*H;
        float a0 = ar[t], a1 = ar[t+256];
        ae0 += we[n]*a0; ae1 += we[n]*a1;
        at0 += wt[n]*a0; at1 += wt[n]*a1;
    }
    atomicAdd(&ctx[b*H+t],      ae0); atomicAdd(&ctx[b*H+t+256],  ae1);
    atomicAdd(&ctxt[b*H+t],     at0); atomicAdd(&ctxt[b*H+t+256], at1);
}

// ---- MFMA pointer scores — one S GEMM, two tanh epilogues (d_se folded here) ----
template<bool BF16A>
__global__ __launch_bounds__(256) void k_probs_mfma(
    const float* __restrict__ Af, const unsigned short* __restrict__ Abf,
    const unsigned short* __restrict__ Wp,
    const float* __restrict__ d_pe, const float* __restrict__ d_pt,
    const float* __restrict__ d_se,
    const float* __restrict__ ptr_v, float* __restrict__ probs)
{
    __shared__ __align__(16) unsigned short As[128*64];
    __shared__ __align__(16) unsigned short Bs[128*64];
    int blk = blockIdx.x;
    int b = blk >> 4; int nt = (blk >> 2) & 3; int ht = blk & 3;
    int n0 = nt*128, hb = ht*128;

    int t = threadIdx.x;
    int lane = t & 63, wave = t >> 6;
    int wy = wave >> 1, wx = wave & 1;
    int li = lane & 15, quad = lane >> 4;

    floatx4 acc[4][4];
    #pragma unroll
    for (int i=0;i<4;++i)
      #pragma unroll
      for (int j=0;j<4;++j) acc[i][j] = (floatx4)(0.0f);

    for (int kt=0; kt<8; ++kt){
        int k0 = kt*64;
        #pragma unroll
        for (int c=0;c<4;++c){
            int idx = c*256 + t;
            int row = idx >> 3, kb = idx & 7;
            if constexpr (BF16A){
                uint4 v = *(const uint4*)&Abf[(size_t)(b*N+n0+row)*H + k0 + kb*8];
                *(uint4*)&As[row*64 + ((kb ^ (row&7))*8)] = v;
            } else {
                const float* src = Af + (size_t)(b*N+n0+row)*H + k0 + kb*8;
                float4 lo = *(const float4*)src;
                float4 hi = *(const float4*)(src+4);
                uint4 p;
                p.x = pk2(lo.x,lo.y); p.y = pk2(lo.z,lo.w);
                p.z = pk2(hi.x,hi.y); p.w = pk2(hi.z,hi.w);
                *(uint4*)&As[row*64 + ((kb ^ (row&7))*8)] = p;
            }
        }
        #pragma unroll
        for (int c=0;c<4;++c){
            int idx = c*256 + t;
            int row = idx >> 3, kb = idx & 7;
            uint4 v = *(const uint4*)&Wp[(size_t)(hb+row)*H + k0 + kb*8];
            *(uint4*)&Bs[row*64 + ((kb ^ (row&7))*8)] = v;
        }
        __syncthreads();
        #pragma unroll
        for (int ks=0;ks<2;++ks){
            short8 af[4], bg[4];
            #pragma unroll
            for (int i=0;i<4;++i){
                int m = wy*64 + i*16 + li;
                int kb = (ks*4 + quad) ^ (m&7);
                af[i] = *(const short8*)&As[m*64 + kb*8];
            }
            #pragma unroll
            for (int j=0;j<4;++j){
                int h = wx*64 + j*16 + li;
                int kb = (ks*4 + quad) ^ (h&7);
                bg[j] = *(const short8*)&Bs[h*64 + kb*8];
            }
            #pragma unroll
            for (int i=0;i<4;++i)
              #pragma unroll
              for (int j=0;j<4;++j)
                acc[i][j] = __builtin_amdgcn_mfma_f32_16x16x32_bf16(af[i], bg[j], acc[i][j], 0,0,0);
        }
        __syncthreads();
    }
    float nsum[4][4];
    #pragma unroll
    for (int i=0;i<4;++i){ nsum[i][0]=0.f;nsum[i][1]=0.f;nsum[i][2]=0.f;nsum[i][3]=0.f; }
    #pragma unroll
    for (int j=0;j<4;++j){
        int hm = hb + wx*64 + j*16 + li;
        float se = d_se[b*H + hm];
        float de = d_pe[b*H + hm] + se;
        float dt = d_pt[b*H + hm] + se;
        float vj = ptr_v[hm];
        #pragma unroll
        for (int i=0;i<4;++i)
          #pragma unroll
          for (int rg=0;rg<4;++rg){
            float s = acc[i][j][rg];
            nsum[i][rg] += vj * (5.0f*fast_tanh(s + de) + fast_tanh(s + dt));
          }
    }
    #pragma unroll
    for (int off=1; off<16; off<<=1)
      #pragma unroll
      for (int i=0;i<4;++i)
        #pragma unroll
        for (int rg=0;rg<4;++rg)
          nsum[i][rg] += __shfl_xor(nsum[i][rg], off);
    if (li==0){
        #pragma unroll
        for (int i=0;i<4;++i)
          #pragma unroll
          for (int rg=0;rg<4;++rg)
            atomicAdd(&probs[b*N + n0 + wy*64 + i*16 + quad*4 + rg], nsum[i][rg]);
    }
}

extern "C" void kernel_launch(void* const* d_in, const int* in_sizes, int n_in,
                              void* d_out, int out_size, void* d_ws, size_t ws_size,
                              hipStream_t stream)
{
    (void)in_sizes; (void)n_in; (void)out_size;
    const float* A    = (const float*)d_in[0];
    const float* sem  = (const float*)d_in[1];
    const float* dec  = (const float*)d_in[2];
    const float* tgt  = (const float*)d_in[3];
    const float* lhh  = (const float*)d_in[4];
    const float* ptrv = (const float*)d_in[5];
    const float* ptrW = (const float*)d_in[6];
    const float* encv = (const float*)d_in[7];
    const float* encW = (const float*)d_in[8];
    const float* tgtv = (const float*)d_in[9];
    const float* tgtW = (const float*)d_in[10];
    const float* wih  = (const float*)d_in[11];
    const float* whh  = (const float*)d_in[12];
    const float* bih  = (const float*)d_in[13];
    const float* bhh  = (const float*)d_in[14];

    float* probs_out = (float*)d_out;
    float* hh_out    = (float*)d_out + B*N;

    float* ws = (float*)d_ws;
    const size_t S = (size_t)B*H;          // 65536
    float* d_enc = ws;
    float* d_tgt = ws + S;
    float* d_se  = ws + 2*S;
    float* sc_e  = ws + 3*S;
    float* sc_t  = ws + 4*S;
    float* ctx   = ws + 5*S;
    float* ctxt  = ws + 6*S;
    float* w_e   = ws + 7*S;
    float* w_t   = ws + 8*S;
    float* d_pe  = ws + 9*S;
    float* d_pt  = ws + 10*S;
    float* gx    = ws + 11*S;              // 3S
    float* gh    = ws + 14*S;              // 3S
    unsigned short* bfb  = (unsigned short*)(ws + 17*S);
    const size_t WH = (size_t)H*H;         // 262144
    const size_t WG = (size_t)3*H*H;       // 786432 (GRU weight)
    unsigned short* We_s  = bfb;
    unsigned short* Wt_s  = We_s + WH;
    unsigned short* Wp_s  = Wt_s + WH;
    unsigned short* We_d  = Wp_s + WH;
    unsigned short* Wt_d  = We_d + WH;
    unsigned short* Wp_c  = Wt_d + WH;
    unsigned short* Wp_e  = Wp_c + WH;
    unsigned short* Wih_b = Wp_e + WH;
    unsigned short* Whh_b = Wih_b + WG;
    unsigned short* Xbf   = Whh_b + WG;
    unsigned short* Hbf   = Xbf + S;
    unsigned short* Tbf   = Hbf + S;
    unsigned short* Sbf   = Tbf + S;
    unsigned short* HNbf  = Sbf + S;
    unsigned short* CXbf  = HNbf + S;
    unsigned short* CTbf  = CXbf + S;
    unsigned short* Abf   = CTbf + S;

    const size_t need_full = 17*S*sizeof(float)
        + (7*WH + 2*WG + 7*S + (size_t)B*N*H) * sizeof(unsigned short);
    const bool big = ws_size >= need_full;

    hipMemsetAsync(sc_e, 0, 4*S*sizeof(float), stream);   // sc_e, sc_t, ctx, ctxt
    hipMemsetAsync(probs_out, 0, (size_t)B*N*sizeof(float), stream);

    k_castw<<<6656, 256, 0, stream>>>(encW, tgtW, ptrW, wih, whh,
        We_s, Wt_s, Wp_s, We_d, Wt_d, Wp_c, Wp_e, Wih_b, Whh_b);
    k_castX<<<128, 256, 0, stream>>>(dec, lhh, tgt, sem, Xbf, Hbf, Tbf, Sbf);
    if (big) k_castA<<<(int)(((size_t)B*N*H)/(256*8)), 256, 0, stream>>>(A, Abf);

    k_gru_gemm<<<24, 256, 0, stream>>>(Xbf, Hbf, Wih_b, Whh_b, gx, gh);
    k_gru_gate<<<256, 256, 0, stream>>>(gx, gh, lhh, bih, bhh, hh_out, HNbf);
    k_bias_gemm<<<12, 256, 0, stream>>>(HNbf, Tbf, Sbf, We_d, Wt_d, Wp_e, d_enc, d_tgt, d_se);

    if (big)
        k_scores_fused<true ><<<2048, 256, 0, stream>>>(A, Abf, We_s, Wt_s, d_enc, d_tgt, encv, tgtv, sc_e, sc_t);
    else
        k_scores_fused<false><<<2048, 256, 0, stream>>>(A, Abf, We_s, Wt_s, d_enc, d_tgt, encv, tgtv, sc_e, sc_t);
    k_softmax<<<B, 256, 0, stream>>>(sc_e, sc_t, w_e, w_t);
    if (big)
        k_context_bf16<<<B*8, 256, 0, stream>>>(Abf, w_e, w_t, ctx, ctxt);
    else
        k_context<<<B*4, 256, 0, stream>>>(A, w_e, w_t, ctx, ctxt);

    k_castctx<<<64, 256, 0, stream>>>(ctx, ctxt, CXbf, CTbf);
    k_dptr_gemm<<<8, 256, 0, stream>>>(CXbf, CTbf, Wp_c, d_pe, d_pt);

    if (big)
        k_probs_mfma<true ><<<2048, 256, 0, stream>>>(A, Abf, Wp_s, d_pe, d_pt, d_se, ptrv, probs_out);
    else
        k_probs_mfma<false><<<2048, 256, 0, stream>>>(A, Abf, Wp_s, d_pe, d_pt, d_se, ptrv, probs_out);
}

// Round 5
// 472.922 us; speedup vs baseline: 3.8467x; 1.0664x over previous
//
#include <hip/hip_runtime.h>
#include <math.h>

#define B 128
#define N 512
#define H 512

typedef __attribute__((ext_vector_type(8))) short short8;
typedef __attribute__((ext_vector_type(4))) float floatx4;

typedef const __attribute__((address_space(1))) unsigned int* gas_t;
typedef __attribute__((address_space(3))) unsigned int* las_t;

// async global->LDS 16B (wave-uniform base + lane*16; our lds addr IS linear in lane)
__device__ __forceinline__ void gl16(const void* g, void* l){
    __builtin_amdgcn_global_load_lds((gas_t)g, (las_t)l, 16, 0, 0);
}

__device__ __forceinline__ float sigmoidf_(float x){ return 1.0f/(1.0f+__expf(-x)); }

__device__ __forceinline__ float fast_tanh(float x){
    float t = __expf(-2.0f*fabsf(x));
    float r = __fdividef(1.0f - t, 1.0f + t);
    return copysignf(r, x);
}

// fp32 -> bf16 RNE
__device__ __forceinline__ unsigned f2bf1(float f){
    unsigned u = __float_as_uint(f);
    u += 0x7FFFu + ((u>>16)&1u);
    return u>>16;
}
__device__ __forceinline__ unsigned pk2(float a, float b){
    return f2bf1(a) | (f2bf1(b)<<16);
}

// ===== one fused cast kernel: weights (6656 rows) + small acts (128) + static A (16384) =====
__global__ __launch_bounds__(256) void k_cast_all(
    const float* __restrict__ encW, const float* __restrict__ tgtW,
    const float* __restrict__ ptrW, const float* __restrict__ wih,
    const float* __restrict__ whh,
    const float* __restrict__ dec, const float* __restrict__ lhh,
    const float* __restrict__ tgt, const float* __restrict__ sem,
    const float* __restrict__ A,
    unsigned short* __restrict__ We_s, unsigned short* __restrict__ Wt_s,
    unsigned short* __restrict__ Wp_s, unsigned short* __restrict__ We_d,
    unsigned short* __restrict__ Wt_d, unsigned short* __restrict__ Wp_c,
    unsigned short* __restrict__ Wp_e, unsigned short* __restrict__ Wih_b,
    unsigned short* __restrict__ Whh_b,
    unsigned short* __restrict__ Xbf, unsigned short* __restrict__ Hbf,
    unsigned short* __restrict__ Tbf, unsigned short* __restrict__ Sbf,
    unsigned short* __restrict__ Abf)
{
    int r = blockIdx.x, t = threadIdx.x;
    if (r < 6656){
        const float* src; unsigned short* dst; int pitch, off, row;
        if (r < 512)      { src=encW; dst=We_s; pitch=2*H; off=0;   row=r; }
        else if (r<1024)  { src=tgtW; dst=Wt_s; pitch=2*H; off=0;   row=r-512; }
        else if (r<1536)  { src=ptrW; dst=Wp_s; pitch=3*H; off=0;   row=r-1024; }
        else if (r<2048)  { src=encW; dst=We_d; pitch=2*H; off=H;   row=r-1536; }
        else if (r<2560)  { src=tgtW; dst=Wt_d; pitch=2*H; off=H;   row=r-2048; }
        else if (r<3072)  { src=ptrW; dst=Wp_c; pitch=3*H; off=H;   row=r-2560; }
        else if (r<3584)  { src=ptrW; dst=Wp_e; pitch=3*H; off=2*H; row=r-3072; }
        else if (r<5120)  { src=wih;  dst=Wih_b;pitch=H;   off=0;   row=r-3584; }
        else              { src=whh;  dst=Whh_b;pitch=H;   off=0;   row=r-5120; }
        float2 v = *(const float2*)&src[(size_t)row*pitch + off + 2*t];
        *(unsigned*)&dst[(size_t)row*H + 2*t] = pk2(v.x, v.y);
    } else if (r < 6784){
        int blk = r - 6656; int mat = blk >> 5;
        const float* src = mat==0?dec : mat==1?lhh : mat==2?tgt : sem;
        unsigned short* dst = mat==0?Xbf : mat==1?Hbf : mat==2?Tbf : Sbf;
        size_t i = ((size_t)(blk&31)*256 + t)*8;
        float4 lo = *(const float4*)&src[i];
        float4 hi = *(const float4*)&src[i+4];
        uint4 p;
        p.x = pk2(lo.x,lo.y); p.y = pk2(lo.z,lo.w);
        p.z = pk2(hi.x,hi.y); p.w = pk2(hi.z,hi.w);
        *(uint4*)&dst[i] = p;
    } else {
        size_t i = ((size_t)(r-6784)*256 + t)*8;
        float4 lo = *(const float4*)&A[i];
        float4 hi = *(const float4*)&A[i+4];
        uint4 p;
        p.x = pk2(lo.x,lo.y); p.y = pk2(lo.z,lo.w);
        p.z = pk2(hi.x,hi.y); p.w = pk2(hi.z,hi.w);
        *(uint4*)&Abf[i] = p;
    }
}

// ===== shared 128x128x512 bf16 MFMA tile: C = A @ B^T (async LDS staging) =====
__device__ __forceinline__ void gemm128_tile(
    const unsigned short* __restrict__ Ab,   // 128 x 512 row-major bf16
    const unsigned short* __restrict__ Bb,   // 128 x 512 row-major bf16
    float* __restrict__ C, int ldc)
{
    __shared__ __align__(16) unsigned short As[128*64];
    __shared__ __align__(16) unsigned short Bs[128*64];
    int t = threadIdx.x;
    int lane = t & 63, wave = t >> 6;
    int wy = wave >> 1, wx = wave & 1;
    int li = lane & 15, quad = lane >> 4;

    floatx4 acc[4][4];
    #pragma unroll
    for (int i=0;i<4;++i)
      #pragma unroll
      for (int j=0;j<4;++j) acc[i][j] = (floatx4)(0.0f);

    for (int kt=0; kt<8; ++kt){
        int k0 = kt*64;
        #pragma unroll
        for (int c=0;c<4;++c){
            int s = c*256 + t;
            int row = s >> 3;
            int kb = (s & 7) ^ (row & 7);
            gl16(&Ab[(size_t)row*512 + k0 + kb*8], &As[(size_t)s*8]);
            gl16(&Bb[(size_t)row*512 + k0 + kb*8], &Bs[(size_t)s*8]);
        }
        __syncthreads();
        #pragma unroll
        for (int ks=0;ks<2;++ks){
            short8 af[4], bg[4];
            #pragma unroll
            for (int i=0;i<4;++i){
                int m = wy*64 + i*16 + li;
                int kb = (ks*4 + quad) ^ (m&7);
                af[i] = *(const short8*)&As[m*64 + kb*8];
            }
            #pragma unroll
            for (int j=0;j<4;++j){
                int h = wx*64 + j*16 + li;
                int kb = (ks*4 + quad) ^ (h&7);
                bg[j] = *(const short8*)&Bs[h*64 + kb*8];
            }
            #pragma unroll
            for (int i=0;i<4;++i)
              #pragma unroll
              for (int j=0;j<4;++j)
                acc[i][j] = __builtin_amdgcn_mfma_f32_16x16x32_bf16(af[i], bg[j], acc[i][j], 0,0,0);
        }
        __syncthreads();
    }
    #pragma unroll
    for (int i=0;i<4;++i)
      #pragma unroll
      for (int j=0;j<4;++j)
        #pragma unroll
        for (int rg=0;rg<4;++rg){
            int m = wy*64 + i*16 + quad*4 + rg;
            int n = wx*64 + j*16 + li;
            C[(size_t)m*ldc + n] = acc[i][j][rg];
        }
}

// variant with fp32 A input (inline cvt staging), bf16 B async
__device__ __forceinline__ void gemm128_tile_f32A(
    const float* __restrict__ Af,            // 128 x 512 row-major fp32
    const unsigned short* __restrict__ Bb,   // 128 x 512 row-major bf16
    float* __restrict__ C, int ldc)
{
    __shared__ __align__(16) unsigned short As[128*64];
    __shared__ __align__(16) unsigned short Bs[128*64];
    int t = threadIdx.x;
    int lane = t & 63, wave = t >> 6;
    int wy = wave >> 1, wx = wave & 1;
    int li = lane & 15, quad = lane >> 4;

    floatx4 acc[4][4];
    #pragma unroll
    for (int i=0;i<4;++i)
      #pragma unroll
      for (int j=0;j<4;++j) acc[i][j] = (floatx4)(0.0f);

    for (int kt=0; kt<8; ++kt){
        int k0 = kt*64;
        #pragma unroll
        for (int c=0;c<4;++c){
            int s = c*256 + t;
            int row = s >> 3;
            int kb = (s & 7) ^ (row & 7);
            gl16(&Bb[(size_t)row*512 + k0 + kb*8], &Bs[(size_t)s*8]);
            const float* src = Af + (size_t)row*512 + k0 + kb*8;
            float4 lo = *(const float4*)src;
            float4 hi = *(const float4*)(src+4);
            uint4 p;
            p.x = pk2(lo.x,lo.y); p.y = pk2(lo.z,lo.w);
            p.z = pk2(hi.x,hi.y); p.w = pk2(hi.z,hi.w);
            *(uint4*)&As[(size_t)s*8] = p;
        }
        __syncthreads();
        #pragma unroll
        for (int ks=0;ks<2;++ks){
            short8 af[4], bg[4];
            #pragma unroll
            for (int i=0;i<4;++i){
                int m = wy*64 + i*16 + li;
                int kb = (ks*4 + quad) ^ (m&7);
                af[i] = *(const short8*)&As[m*64 + kb*8];
            }
            #pragma unroll
            for (int j=0;j<4;++j){
                int h = wx*64 + j*16 + li;
                int kb = (ks*4 + quad) ^ (h&7);
                bg[j] = *(const short8*)&Bs[h*64 + kb*8];
            }
            #pragma unroll
            for (int i=0;i<4;++i)
              #pragma unroll
              for (int j=0;j<4;++j)
                acc[i][j] = __builtin_amdgcn_mfma_f32_16x16x32_bf16(af[i], bg[j], acc[i][j], 0,0,0);
        }
        __syncthreads();
    }
    #pragma unroll
    for (int i=0;i<4;++i)
      #pragma unroll
      for (int j=0;j<4;++j)
        #pragma unroll
        for (int rg=0;rg<4;++rg){
            int m = wy*64 + i*16 + quad*4 + rg;
            int n = wx*64 + j*16 + li;
            C[(size_t)m*ldc + n] = acc[i][j][rg];
        }
}

// ---- GRU gates GEMM: gx = X@Wih^T, gh = H@Whh^T (grid 24) ----
__global__ __launch_bounds__(256,2) void k_gru_gemm(
    const unsigned short* __restrict__ Xbf, const unsigned short* __restrict__ Hbf,
    const unsigned short* __restrict__ Wih_b, const unsigned short* __restrict__ Whh_b,
    float* __restrict__ gx, float* __restrict__ gh)
{
    int blk = blockIdx.x;
    int mat = blk / 12, nt = blk % 12;
    const unsigned short* Ab = mat ? Hbf : Xbf;
    const unsigned short* Bb = (mat ? Whh_b : Wih_b) + (size_t)nt*128*512;
    float* C = (mat ? gh : gx) + nt*128;
    gemm128_tile(Ab, Bb, C, 3*H);
}

// ---- GRU elementwise gates ----
__global__ __launch_bounds__(256) void k_gru_gate(const float* __restrict__ gx,
    const float* __restrict__ gh, const float* __restrict__ lhh,
    const float* __restrict__ bih, const float* __restrict__ bhh,
    float* __restrict__ out_hh, unsigned short* __restrict__ hnew_bf)
{
    int idx = blockIdx.x*256 + threadIdx.x;   // 0..65535
    int b = idx >> 9, k = idx & 511;
    const float* gxb = gx + (size_t)b*(3*H);
    const float* ghb = gh + (size_t)b*(3*H);
    float r = sigmoidf_(gxb[k]     + bih[k]     + ghb[k]     + bhh[k]);
    float z = sigmoidf_(gxb[H+k]   + bih[H+k]   + ghb[H+k]   + bhh[H+k]);
    float n = tanhf(gxb[2*H+k] + bih[2*H+k] + r*(ghb[2*H+k] + bhh[2*H+k]));
    float h = (1.f-z)*n + z*lhh[idx];
    out_hh[idx] = h;
    hnew_bf[idx] = (unsigned short)f2bf1(h);
}

// ---- broadcast-half biases GEMM (grid 12) ----
__global__ __launch_bounds__(256,2) void k_bias_gemm(
    const unsigned short* __restrict__ HNbf, const unsigned short* __restrict__ Tbf,
    const unsigned short* __restrict__ Sbf,
    const unsigned short* __restrict__ We_d, const unsigned short* __restrict__ Wt_d,
    const unsigned short* __restrict__ Wp_e,
    float* __restrict__ d_enc, float* __restrict__ d_tgt, float* __restrict__ d_se)
{
    int blk = blockIdx.x;
    int mat = blk >> 2, nt = blk & 3;
    const unsigned short* Ab = mat==0 ? HNbf : mat==1 ? Tbf : Sbf;
    const unsigned short* Bb = (mat==0 ? We_d : mat==1 ? Wt_d : Wp_e) + (size_t)nt*128*512;
    float* C = (mat==0 ? d_enc : mat==1 ? d_tgt : d_se) + nt*128;
    gemm128_tile(Ab, Bb, C, H);
}

// ---- pointer biases GEMM (grid 8): fp32 ctx/ctxt staged inline (no castctx kernel) ----
__global__ __launch_bounds__(256,2) void k_dptr_gemm(
    const float* __restrict__ ctx, const float* __restrict__ ctxt,
    const unsigned short* __restrict__ Wp_c,
    float* __restrict__ d_pe, float* __restrict__ d_pt)
{
    int blk = blockIdx.x;
    int mat = blk >> 2, nt = blk & 3;
    const float* Af = mat ? ctxt : ctx;
    const unsigned short* Bb = Wp_c + (size_t)nt*128*512;
    float* C = (mat ? d_pt : d_pe) + nt*128;
    gemm128_tile_f32A(Af, Bb, C, H);
}

// ---- fused enc+tgt MFMA scores (grid 2048), async LDS staging ----
template<bool BF16A>
__global__ __launch_bounds__(256,2) void k_scores_fused(
    const float* __restrict__ Af, const unsigned short* __restrict__ Abf,
    const unsigned short* __restrict__ We, const unsigned short* __restrict__ Wt,
    const float* __restrict__ d_enc, const float* __restrict__ d_tgt,
    const float* __restrict__ enc_v, const float* __restrict__ tgt_v,
    float* __restrict__ sc_e, float* __restrict__ sc_t)
{
    __shared__ __align__(16) unsigned short As[128*64];
    __shared__ __align__(16) unsigned short Be[128*64];
    __shared__ __align__(16) unsigned short Bt[128*64];
    int blk = blockIdx.x;
    int b = blk >> 4; int nt = (blk >> 2) & 3; int ht = blk & 3;
    int n0 = nt*128, hb = ht*128;
    int t = threadIdx.x;
    int lane = t & 63, wave = t >> 6;
    int wy = wave >> 1, wx = wave & 1;
    int li = lane & 15, quad = lane >> 4;

    floatx4 acc_e[4][4], acc_t[4][4];
    #pragma unroll
    for (int i=0;i<4;++i)
      #pragma unroll
      for (int j=0;j<4;++j){ acc_e[i][j]=(floatx4)(0.0f); acc_t[i][j]=(floatx4)(0.0f); }

    for (int kt=0; kt<8; ++kt){
        int k0 = kt*64;
        #pragma unroll
        for (int c=0;c<4;++c){
            int s = c*256 + t;
            int row = s >> 3;
            int kb = (s & 7) ^ (row & 7);
            if constexpr (BF16A){
                gl16(&Abf[(size_t)(b*N+n0+row)*H + k0 + kb*8], &As[(size_t)s*8]);
            } else {
                const float* src = Af + (size_t)(b*N+n0+row)*H + k0 + kb*8;
                float4 lo = *(const float4*)src;
                float4 hi = *(const float4*)(src+4);
                uint4 p;
                p.x = pk2(lo.x,lo.y); p.y = pk2(lo.z,lo.w);
                p.z = pk2(hi.x,hi.y); p.w = pk2(hi.z,hi.w);
                *(uint4*)&As[(size_t)s*8] = p;
            }
            gl16(&We[(size_t)(hb+row)*H + k0 + kb*8], &Be[(size_t)s*8]);
            gl16(&Wt[(size_t)(hb+row)*H + k0 + kb*8], &Bt[(size_t)s*8]);
        }
        __syncthreads();
        #pragma unroll
        for (int ks=0;ks<2;++ks){
            short8 af[4], be[4], bt[4];
            #pragma unroll
            for (int i=0;i<4;++i){
                int m = wy*64 + i*16 + li;
                int kb = (ks*4 + quad) ^ (m&7);
                af[i] = *(const short8*)&As[m*64 + kb*8];
            }
            #pragma unroll
            for (int j=0;j<4;++j){
                int h = wx*64 + j*16 + li;
                int kb = (ks*4 + quad) ^ (h&7);
                be[j] = *(const short8*)&Be[h*64 + kb*8];
                bt[j] = *(const short8*)&Bt[h*64 + kb*8];
            }
            #pragma unroll
            for (int i=0;i<4;++i)
              #pragma unroll
              for (int j=0;j<4;++j){
                acc_e[i][j] = __builtin_amdgcn_mfma_f32_16x16x32_bf16(af[i], be[j], acc_e[i][j], 0,0,0);
                acc_t[i][j] = __builtin_amdgcn_mfma_f32_16x16x32_bf16(af[i], bt[j], acc_t[i][j], 0,0,0);
              }
        }
        __syncthreads();
    }
    float nse[4][4], nst[4][4];
    #pragma unroll
    for (int i=0;i<4;++i)
      #pragma unroll
      for (int rg=0;rg<4;++rg){ nse[i][rg]=0.f; nst[i][rg]=0.f; }
    #pragma unroll
    for (int j=0;j<4;++j){
        int hm = hb + wx*64 + j*16 + li;
        float dje = d_enc[b*H+hm], vje = enc_v[hm];
        float djt = d_tgt[b*H+hm], vjt = tgt_v[hm];
        #pragma unroll
        for (int i=0;i<4;++i)
          #pragma unroll
          for (int rg=0;rg<4;++rg){
            nse[i][rg] += vje * fast_tanh(acc_e[i][j][rg] + dje);
            nst[i][rg] += vjt * fast_tanh(acc_t[i][j][rg] + djt);
          }
    }
    #pragma unroll
    for (int off=1; off<16; off<<=1)
      #pragma unroll
      for (int i=0;i<4;++i)
        #pragma unroll
        for (int rg=0;rg<4;++rg){
          nse[i][rg] += __shfl_xor(nse[i][rg], off);
          nst[i][rg] += __shfl_xor(nst[i][rg], off);
        }
    if (li==0){
        #pragma unroll
        for (int i=0;i<4;++i)
          #pragma unroll
          for (int rg=0;rg<4;++rg){
            atomicAdd(&sc_e[b*N + n0 + wy*64 + i*16 + quad*4 + rg], nse[i][rg]);
            atomicAdd(&sc_t[b*N + n0 + wy*64 + i*16 + quad*4 + rg], nst[i][rg]);
          }
    }
}

// ---------------- softmax both score rows ----------------
__global__ __launch_bounds__(256) void k_softmax(const float* __restrict__ sc_e,
    const float* __restrict__ sc_t, float* __restrict__ w_e, float* __restrict__ w_t)
{
    __shared__ float buf[256];
    int b = blockIdx.x, t = threadIdx.x;
    float x0 = sc_e[b*N+t], x1 = sc_e[b*N+t+256];
    float m = fmaxf(x0,x1);
    buf[t]=m; __syncthreads();
    for (int s2=128;s2>0;s2>>=1){ if(t<s2) buf[t]=fmaxf(buf[t],buf[t+s2]); __syncthreads(); }
    m = buf[0]; __syncthreads();
    float e0 = __expf(x0-m), e1 = __expf(x1-m);
    buf[t]=e0+e1; __syncthreads();
    for (int s2=128;s2>0;s2>>=1){ if(t<s2) buf[t]+=buf[t+s2]; __syncthreads(); }
    float inv = 1.0f/buf[0]; __syncthreads();
    w_e[b*N+t]=e0*inv; w_e[b*N+t+256]=e1*inv;
    x0 = sc_t[b*N+t]; x1 = sc_t[b*N+t+256];
    m = fmaxf(x0,x1);
    buf[t]=m; __syncthreads();
    for (int s2=128;s2>0;s2>>=1){ if(t<s2) buf[t]=fmaxf(buf[t],buf[t+s2]); __syncthreads(); }
    m = buf[0]; __syncthreads();
    e0 = __expf(x0-m); e1 = __expf(x1-m);
    buf[t]=e0+e1; __syncthreads();
    for (int s2=128;s2>0;s2>>=1){ if(t<s2) buf[t]+=buf[t+s2]; __syncthreads(); }
    inv = 1.0f/buf[0];
    w_t[b*N+t]=e0*inv; w_t[b*N+t+256]=e1*inv;
}

// ---------------- context from bf16 A ----------------
__global__ __launch_bounds__(256) void k_context_bf16(const unsigned short* __restrict__ Abf,
    const float* __restrict__ w_e, const float* __restrict__ w_t,
    float* __restrict__ ctx, float* __restrict__ ctxt)
{
    __shared__ float we[64], wt[64];
    int b = blockIdx.x >> 3, c = blockIdx.x & 7, t = threadIdx.x;
    int n0 = c*64;
    if (t < 64){ we[t]=w_e[b*N+n0+t]; wt[t]=w_t[b*N+n0+t]; }
    __syncthreads();
    float ae0=0.f, ae1=0.f, at0=0.f, at1=0.f;
    for (int n=0;n<64;++n){
        unsigned u = *(const unsigned*)&Abf[(size_t)(b*N+n0+n)*H + 2*t];
        float lo = __uint_as_float(u<<16);
        float hi = __uint_as_float(u & 0xFFFF0000u);
        float e = we[n], g = wt[n];
        ae0 += e*lo; ae1 += e*hi; at0 += g*lo; at1 += g*hi;
    }
    atomicAdd(&ctx[b*H+2*t],   ae0); atomicAdd(&ctx[b*H+2*t+1],  ae1);
    atomicAdd(&ctxt[b*H+2*t],  at0); atomicAdd(&ctxt[b*H+2*t+1], at1);
}

// ---------------- context from fp32 A (fallback) ----------------
__global__ __launch_bounds__(256) void k_context(const float* __restrict__ A,
    const float* __restrict__ w_e, const float* __restrict__ w_t,
    float* __restrict__ ctx, float* __restrict__ ctxt)
{
    __shared__ float we[128], wt[128];
    int b = blockIdx.x >> 2, c = blockIdx.x & 3, t = threadIdx.x;
    int n0 = c*128;
    if (t < 128){ we[t]=w_e[b*N+n0+t]; wt[t]=w_t[b*N+n0+t]; }
    __syncthreads();
    float ae0=0.f, ae1=0.f, at0=0.f, at1=0.f;
    for (int n=0;n<128;++n){
        const float* ar = A + (size_t)(b*N + n0 + n)*H;
        float a0 = ar[t], a1 = ar[t+256];
        ae0 += we[n]*a0; ae1 += we[n]*a1;
        at0 += wt[n]*a0; at1 += wt[n]*a1;
    }
    atomicAdd(&ctx[b*H+t],      ae0); atomicAdd(&ctx[b*H+t+256],  ae1);
    atomicAdd(&ctxt[b*H+t],     at0); atomicAdd(&ctxt[b*H+t+256], at1);
}

// ---- MFMA pointer scores — one S GEMM, two tanh epilogues, async staging ----
template<bool BF16A>
__global__ __launch_bounds__(256,2) void k_probs_mfma(
    const float* __restrict__ Af, const unsigned short* __restrict__ Abf,
    const unsigned short* __restrict__ Wp,
    const float* __restrict__ d_pe, const float* __restrict__ d_pt,
    const float* __restrict__ d_se,
    const float* __restrict__ ptr_v, float* __restrict__ probs)
{
    __shared__ __align__(16) unsigned short As[128*64];
    __shared__ __align__(16) unsigned short Bs[128*64];
    int blk = blockIdx.x;
    int b = blk >> 4; int nt = (blk >> 2) & 3; int ht = blk & 3;
    int n0 = nt*128, hb = ht*128;

    int t = threadIdx.x;
    int lane = t & 63, wave = t >> 6;
    int wy = wave >> 1, wx = wave & 1;
    int li = lane & 15, quad = lane >> 4;

    floatx4 acc[4][4];
    #pragma unroll
    for (int i=0;i<4;++i)
      #pragma unroll
      for (int j=0;j<4;++j) acc[i][j] = (floatx4)(0.0f);

    for (int kt=0; kt<8; ++kt){
        int k0 = kt*64;
        #pragma unroll
        for (int c=0;c<4;++c){
            int s = c*256 + t;
            int row = s >> 3;
            int kb = (s & 7) ^ (row & 7);
            if constexpr (BF16A){
                gl16(&Abf[(size_t)(b*N+n0+row)*H + k0 + kb*8], &As[(size_t)s*8]);
            } else {
                const float* src = Af + (size_t)(b*N+n0+row)*H + k0 + kb*8;
                float4 lo = *(const float4*)src;
                float4 hi = *(const float4*)(src+4);
                uint4 p;
                p.x = pk2(lo.x,lo.y); p.y = pk2(lo.z,lo.w);
                p.z = pk2(hi.x,hi.y); p.w = pk2(hi.z,hi.w);
                *(uint4*)&As[(size_t)s*8] = p;
            }
            gl16(&Wp[(size_t)(hb+row)*H + k0 + kb*8], &Bs[(size_t)s*8]);
        }
        __syncthreads();
        #pragma unroll
        for (int ks=0;ks<2;++ks){
            short8 af[4], bg[4];
            #pragma unroll
            for (int i=0;i<4;++i){
                int m = wy*64 + i*16 + li;
                int kb = (ks*4 + quad) ^ (m&7);
                af[i] = *(const short8*)&As[m*64 + kb*8];
            }
            #pragma unroll
            for (int j=0;j<4;++j){
                int h = wx*64 + j*16 + li;
                int kb = (ks*4 + quad) ^ (h&7);
                bg[j] = *(const short8*)&Bs[h*64 + kb*8];
            }
            #pragma unroll
            for (int i=0;i<4;++i)
              #pragma unroll
              for (int j=0;j<4;++j)
                acc[i][j] = __builtin_amdgcn_mfma_f32_16x16x32_bf16(af[i], bg[j], acc[i][j], 0,0,0);
        }
        __syncthreads();
    }
    float nsum[4][4];
    #pragma unroll
    for (int i=0;i<4;++i){ nsum[i][0]=0.f;nsum[i][1]=0.f;nsum[i][2]=0.f;nsum[i][3]=0.f; }
    #pragma unroll
    for (int j=0;j<4;++j){
        int hm = hb + wx*64 + j*16 + li;
        float se = d_se[b*H + hm];
        float de = d_pe[b*H + hm] + se;
        float dt = d_pt[b*H + hm] + se;
        float vj = ptr_v[hm];
        #pragma unroll
        for (int i=0;i<4;++i)
          #pragma unroll
          for (int rg=0;rg<4;++rg){
            float s = acc[i][j][rg];
            nsum[i][rg] += vj * (5.0f*fast_tanh(s + de) + fast_tanh(s + dt));
          }
    }
    #pragma unroll
    for (int off=1; off<16; off<<=1)
      #pragma unroll
      for (int i=0;i<4;++i)
        #pragma unroll
        for (int rg=0;rg<4;++rg)
          nsum[i][rg] += __shfl_xor(nsum[i][rg], off);
    if (li==0){
        #pragma unroll
        for (int i=0;i<4;++i)
          #pragma unroll
          for (int rg=0;rg<4;++rg)
            atomicAdd(&probs[b*N + n0 + wy*64 + i*16 + quad*4 + rg], nsum[i][rg]);
    }
}

extern "C" void kernel_launch(void* const* d_in, const int* in_sizes, int n_in,
                              void* d_out, int out_size, void* d_ws, size_t ws_size,
                              hipStream_t stream)
{
    (void)in_sizes; (void)n_in; (void)out_size;
    const float* A    = (const float*)d_in[0];
    const float* sem  = (const float*)d_in[1];
    const float* dec  = (const float*)d_in[2];
    const float* tgt  = (const float*)d_in[3];
    const float* lhh  = (const float*)d_in[4];
    const float* ptrv = (const float*)d_in[5];
    const float* ptrW = (const float*)d_in[6];
    const float* encv = (const float*)d_in[7];
    const float* encW = (const float*)d_in[8];
    const float* tgtv = (const float*)d_in[9];
    const float* tgtW = (const float*)d_in[10];
    const float* wih  = (const float*)d_in[11];
    const float* whh  = (const float*)d_in[12];
    const float* bih  = (const float*)d_in[13];
    const float* bhh  = (const float*)d_in[14];

    float* probs_out = (float*)d_out;
    float* hh_out    = (float*)d_out + B*N;

    float* ws = (float*)d_ws;
    const size_t S = (size_t)B*H;          // 65536
    float* d_enc = ws;
    float* d_tgt = ws + S;
    float* d_se  = ws + 2*S;
    float* sc_e  = ws + 3*S;
    float* sc_t  = ws + 4*S;
    float* ctx   = ws + 5*S;
    float* ctxt  = ws + 6*S;
    float* w_e   = ws + 7*S;
    float* w_t   = ws + 8*S;
    float* d_pe  = ws + 9*S;
    float* d_pt  = ws + 10*S;
    float* gx    = ws + 11*S;              // 3S
    float* gh    = ws + 14*S;              // 3S
    unsigned short* bfb  = (unsigned short*)(ws + 17*S);
    const size_t WH = (size_t)H*H;         // 262144
    const size_t WG = (size_t)3*H*H;
    unsigned short* We_s  = bfb;
    unsigned short* Wt_s  = We_s + WH;
    unsigned short* Wp_s  = Wt_s + WH;
    unsigned short* We_d  = Wp_s + WH;
    unsigned short* Wt_d  = We_d + WH;
    unsigned short* Wp_c  = Wt_d + WH;
    unsigned short* Wp_e  = Wp_c + WH;
    unsigned short* Wih_b = Wp_e + WH;
    unsigned short* Whh_b = Wih_b + WG;
    unsigned short* Xbf   = Whh_b + WG;
    unsigned short* Hbf   = Xbf + S;
    unsigned short* Tbf   = Hbf + S;
    unsigned short* Sbf   = Tbf + S;
    unsigned short* HNbf  = Sbf + S;
    unsigned short* Abf   = HNbf + S;

    const size_t need_full = 17*S*sizeof(float)
        + (7*WH + 2*WG + 5*S + (size_t)B*N*H) * sizeof(unsigned short);
    const bool big = ws_size >= need_full;

    hipMemsetAsync(sc_e, 0, 4*S*sizeof(float), stream);   // sc_e, sc_t, ctx, ctxt
    hipMemsetAsync(probs_out, 0, (size_t)B*N*sizeof(float), stream);

    int castA_blocks = big ? (int)(((size_t)B*N*H)/(256*8)) : 0;
    k_cast_all<<<6784 + castA_blocks, 256, 0, stream>>>(encW, tgtW, ptrW, wih, whh,
        dec, lhh, tgt, sem, A,
        We_s, Wt_s, Wp_s, We_d, Wt_d, Wp_c, Wp_e, Wih_b, Whh_b,
        Xbf, Hbf, Tbf, Sbf, Abf);

    k_gru_gemm<<<24, 256, 0, stream>>>(Xbf, Hbf, Wih_b, Whh_b, gx, gh);
    k_gru_gate<<<256, 256, 0, stream>>>(gx, gh, lhh, bih, bhh, hh_out, HNbf);
    k_bias_gemm<<<12, 256, 0, stream>>>(HNbf, Tbf, Sbf, We_d, Wt_d, Wp_e, d_enc, d_tgt, d_se);

    if (big)
        k_scores_fused<true ><<<2048, 256, 0, stream>>>(A, Abf, We_s, Wt_s, d_enc, d_tgt, encv, tgtv, sc_e, sc_t);
    else
        k_scores_fused<false><<<2048, 256, 0, stream>>>(A, Abf, We_s, Wt_s, d_enc, d_tgt, encv, tgtv, sc_e, sc_t);
    k_softmax<<<B, 256, 0, stream>>>(sc_e, sc_t, w_e, w_t);
    if (big)
        k_context_bf16<<<B*8, 256, 0, stream>>>(Abf, w_e, w_t, ctx, ctxt);
    else
        k_context<<<B*4, 256, 0, stream>>>(A, w_e, w_t, ctx, ctxt);

    k_dptr_gemm<<<8, 256, 0, stream>>>(ctx, ctxt, Wp_c, d_pe, d_pt);

    if (big)
        k_probs_mfma<true ><<<2048, 256, 0, stream>>>(A, Abf, Wp_s, d_pe, d_pt, d_se, ptrv, probs_out);
    else
        k_probs_mfma<false><<<2048, 256, 0, stream>>>(A, Abf, Wp_s, d_pe, d_pt, d_se, ptrv, probs_out);
}